// Round 8
// baseline (328.464 us; speedup 1.0000x reference)
//
#include <hip/hip_runtime.h>
#include <cstdint>

// SpacetimeNonLocalBlock: B=4, C=256, T*H*W=N=6272, IC=128.
// R15: (1) flash11 = flash5 body with TWO k-tiles per barrier epoch:
// double-wide LDS buffers (Ks[2][2 tiles], Vs[2][2 tiles], 68KB), prefetch
// A -> compute tile 2e -> write A + prefetch B -> compute 2e+1 -> write B ->
// ONE __syncthreads. Barriers/block 49 -> 25. Stg regs stay 16 (one set live
// per compute body - avoids R11's spill). Reg tier unchanged (8 waves/CU).
// Tests the barrier-epoch-stall theory; staging mechanism untouched (R8-R11
// showed gload_lds / vmcnt pipelines / S-ahead all regress).
// (2) proj_mfma: c-step 16 -> 32 (barriers 32 -> 16), LDS rows padded to 40
// ushorts -> all b128 reads bank-conflict-free ((5*ln+g) mod 8 permutation).
// wconv/mz = R14 verbatim.

#define BB   4
#define CCH  256
#define NPOS 6272
#define ICH  128
#define BNIC ((size_t)BB * NPOS * ICH)
#define KSPL 4
#define KLEN (NPOS / KSPL)   // 1568
#define TKF  32
#define NITK (KLEN / TKF)    // 49
#define SLACK 12.0f

typedef __attribute__((ext_vector_type(8)))  _Float16 h8v;  // 8 f16 MFMA frag
typedef __attribute__((ext_vector_type(16))) float fx16;    // 32x32 acc

__device__ __forceinline__ unsigned short f2h(float f) {
  _Float16 h = (_Float16)f;
  return __builtin_bit_cast(unsigned short, h);
}
__device__ __forceinline__ unsigned int pkh(float lo, float hi) {
  return __builtin_bit_cast(unsigned int, __builtin_amdgcn_cvt_pkrtz(lo, hi));
}
__device__ __forceinline__ float h2f(unsigned short u) {
  return (float)__builtin_bit_cast(_Float16, u);
}

// ---------------------------------------------------------------------------
// wconv: [Wtheta;Wphi;Wg] (3x128x256 f32) -> Whi/Wlo f16 split. grid 96.
// ---------------------------------------------------------------------------
__global__ __launch_bounds__(256, 1)
void wconv(const float* __restrict__ Wtheta, const float* __restrict__ Wphi,
           const float* __restrict__ Wg,
           unsigned short* __restrict__ Whi, unsigned short* __restrict__ Wlo) {
  const int idx4 = (blockIdx.x * 256 + threadIdx.x) * 4;   // [0, 98304) step 4
  const int p = idx4 >> 15;                                // 0,1,2 (128*256=32768)
  const float* W = (p == 0) ? Wtheta : (p == 1) ? Wphi : Wg;
  const float4 v = *(const float4*)&W[idx4 - (p << 15)];
  const float vv[4] = {v.x, v.y, v.z, v.w};
  ushort4 h, l;
  unsigned short* hp = (unsigned short*)&h;
  unsigned short* lp = (unsigned short*)&l;
  #pragma unroll
  for (int q = 0; q < 4; ++q) {
    _Float16 hh = (_Float16)vv[q];
    hp[q] = __builtin_bit_cast(unsigned short, hh);
    lp[q] = f2h(vv[q] - (float)hh);
  }
  *(ushort4*)&Whi[idx4] = h;
  *(ushort4*)&Wlo[idx4] = l;
}

// ---------------------------------------------------------------------------
// proj_mfma: grid (N/32, B), 256 thr (4 waves). Wave wv owns o-tiles
// T = wv*3 + t: T/4 = proj (0:theta->Qg *log2e, 1:phi->Kg, 2:g->Vtg).
// c-step 32 per epoch (8 epochs, 16 barriers). x staged as f16 hi/lo
// [32n][40c-stride] (b128 reads conflict-free). 2 kc x 3 tiles x 3 terms
// = 18 MFMA per wave per epoch.
// ---------------------------------------------------------------------------
__global__ __launch_bounds__(256, 2)
void proj_mfma(const float* __restrict__ x,
               const unsigned short* __restrict__ Whi,
               const unsigned short* __restrict__ Wlo,
               unsigned short* __restrict__ Qg,
               unsigned short* __restrict__ Kg,
               unsigned short* __restrict__ Vtg) {
  __shared__ unsigned short Xhi[32][40];
  __shared__ unsigned short Xlo[32][40];
  const int n0 = blockIdx.x * 32;
  const int b  = blockIdx.y;
  const int tid = threadIdx.x;
  const int lane = tid & 63, wv = tid >> 6;
  const int ln = lane & 31, g = lane >> 5;

  fx16 acc[3];
  acc[0] = (fx16)(0.0f); acc[1] = (fx16)(0.0f); acc[2] = (fx16)(0.0f);

  // staging: row sn, channels cq..cq+3 of the 32-c chunk
  const int sn = tid & 31, cq = (tid >> 5) * 4;
  const float* xp = x + ((size_t)b * CCH + cq) * NPOS + n0 + sn;

  float pv[4];
  #pragma unroll
  for (int q = 0; q < 4; ++q) pv[q] = xp[(size_t)q * NPOS];

  for (int c0 = 0; c0 < CCH; c0 += 32) {
    {
      ushort4 h4, l4;
      unsigned short* hp = (unsigned short*)&h4;
      unsigned short* lp = (unsigned short*)&l4;
      #pragma unroll
      for (int q = 0; q < 4; ++q) {
        _Float16 hh = (_Float16)pv[q];
        hp[q] = __builtin_bit_cast(unsigned short, hh);
        lp[q] = f2h(pv[q] - (float)hh);
      }
      *(ushort4*)&Xhi[sn][cq] = h4;
      *(ushort4*)&Xlo[sn][cq] = l4;
    }
    if (c0 + 32 < CCH) {
      #pragma unroll
      for (int q = 0; q < 4; ++q) pv[q] = xp[(size_t)(c0 + 32 + q) * NPOS];
    }
    __syncthreads();
    #pragma unroll
    for (int kc = 0; kc < 2; ++kc) {
      const h8v bxh = *(const h8v*)&Xhi[ln][kc * 16 + g * 8];
      const h8v bxl = *(const h8v*)&Xlo[ln][kc * 16 + g * 8];
      #pragma unroll
      for (int t = 0; t < 3; ++t) {
        const int T = wv * 3 + t;
        const size_t wb = ((size_t)(T * 32 + ln)) * CCH + c0 + kc * 16 + g * 8;
        const h8v ah = *(const h8v*)&Whi[wb];
        const h8v al = *(const h8v*)&Wlo[wb];
        acc[t] = __builtin_amdgcn_mfma_f32_32x32x16_f16(ah, bxh, acc[t], 0, 0, 0);
        acc[t] = __builtin_amdgcn_mfma_f32_32x32x16_f16(ah, bxl, acc[t], 0, 0, 0);
        acc[t] = __builtin_amdgcn_mfma_f32_32x32x16_f16(al, bxh, acc[t], 0, 0, 0);
      }
    }
    __syncthreads();
  }

  const float LOG2E = 1.4426950408889634f;
  const int n = n0 + ln;
  #pragma unroll
  for (int t = 0; t < 3; ++t) {
    const int T = wv * 3 + t;
    const int p = T >> 2;
    const int ot = (T & 3) * 32;
    if (p < 2) {
      unsigned short* Out = (p == 0) ? Qg : Kg;
      const float scl = (p == 0) ? LOG2E : 1.0f;
      #pragma unroll
      for (int q = 0; q < 4; ++q) {
        ushort4 v;
        v.x = f2h(acc[t][4 * q + 0] * scl);
        v.y = f2h(acc[t][4 * q + 1] * scl);
        v.z = f2h(acc[t][4 * q + 2] * scl);
        v.w = f2h(acc[t][4 * q + 3] * scl);
        *(ushort4*)&Out[((size_t)b * NPOS + n) * ICH + ot + 8 * q + 4 * g] = v;
      }
    } else {
      #pragma unroll
      for (int r = 0; r < 16; ++r) {
        const int o = ot + (r & 3) + 8 * (r >> 2) + 4 * g;
        Vtg[((size_t)b * ICH + o) * NPOS + n] = f2h(acc[t][r]);
      }
    }
  }
}

// ---------------------------------------------------------------------------
// flash11: flash5 body, 2 k-tiles per barrier epoch. Flat grid 784, XCD-slab
// decode. LDS 68 KB: Ks[2][2x32x128] swz, Vs[2][2x128x36]. 24 epochs
// (tiles 0..47) + tail tile 48. One __syncthreads per epoch (25/block).
// ---------------------------------------------------------------------------
__global__ __launch_bounds__(256, 2)
void flash11(const unsigned short* __restrict__ Qg,
             const unsigned short* __restrict__ Kg,
             const unsigned short* __restrict__ Vtg,
             unsigned short* __restrict__ Opart,
             float* __restrict__ Mpart,
             float* __restrict__ Lpart) {
  __shared__ unsigned short Ks[2][2 * TKF * 128];   // 16 KB per buf
  __shared__ unsigned short Vs[2][2 * 128 * 36];    // 18 KB per buf

  const int f   = blockIdx.x;
  const int xcd = f & 7, j = f >> 3;            // j in [0,98)
  const int hi  = (j >= NITK) ? 1 : 0;
  const int slab = xcd * 2 + hi;                // [0,16)
  const int itile = j - hi * NITK;              // [0,49)
  const int b   = slab >> 2;
  const int spl = slab & 3;
  const int n0  = itile * 128;
  const int kb  = spl * KLEN;

  const int tid = threadIdx.x;
  const int lane = tid & 63, wv = tid >> 6;
  const int qlane = lane & 31, g = lane >> 5;
  const int swz = qlane & 15;

  h8v qf[8];
  {
    const size_t qbase = ((size_t)b * NPOS + n0 + 32 * wv + qlane) * ICH;
    #pragma unroll
    for (int cs = 0; cs < 8; ++cs)
      qf[cs] = *(const h8v*)&Qg[qbase + cs * 16 + g * 8];
  }

  // staging coords (fixed per thread)
  const int kr0 = tid >> 4, kc_ = tid & 15;           // K: rows kr0, kr0+16
  const size_t kgbase = (size_t)b * NPOS + kb;
  const size_t vgbase = (size_t)b * ICH * NPOS + kb;

  // ---- prologue: tiles 0,1 -> buf0 slots 0,1 ----
  #pragma unroll
  for (int t = 0; t < 2; ++t) {
    #pragma unroll
    for (int i = 0; i < 2; ++i) {
      const int kr = kr0 + i * 16;
      const uint4 v = *(const uint4*)&Kg[(kgbase + t * TKF + kr) * ICH + kc_ * 8];
      *(uint4*)&Ks[0][t * 4096 + kr * 128 + (kc_ ^ (kr & 15)) * 8] = v;
      const int idx = tid * 2 + i, dr = idx >> 2, cv = idx & 3;
      const uint4 w = *(const uint4*)&Vtg[vgbase + (size_t)dr * NPOS + t * TKF + cv * 8];
      *(uint2*)&Vs[0][t * 4608 + dr * 36 + cv * 8]     = make_uint2(w.x, w.y);
      *(uint2*)&Vs[0][t * 4608 + dr * 36 + cv * 8 + 4] = make_uint2(w.z, w.w);
    }
  }
  __syncthreads();

  float m_run = -1e30f, m_true = -1e30f, l_run = 0.0f;
  fx16 accO[4];
  #pragma unroll
  for (int mt = 0; mt < 4; ++mt) accO[mt] = (fx16)(0.0f);

  uint4 stgK[2], stgV[2];

  // per-tile compute: QK -> slack-fold softmax -> PV (exact flash5 body)
  auto FTILE = [&](const unsigned short* ksb, const unsigned short* vsb) {
    fx16 accS = (fx16)(0.0f);
    #pragma unroll
    for (int cs = 0; cs < 8; ++cs) {
      const h8v aK = *(const h8v*)&ksb[qlane * 128 + ((2 * cs + g) ^ swz) * 8];
      accS = __builtin_amdgcn_mfma_f32_32x32x16_f16(aK, qf[cs], accS, 0, 0, 0);
    }
    float a0 = fmaxf(accS[0], accS[1]),   a1 = fmaxf(accS[2], accS[3]);
    float a2 = fmaxf(accS[4], accS[5]),   a3 = fmaxf(accS[6], accS[7]);
    float a4 = fmaxf(accS[8], accS[9]),   a5 = fmaxf(accS[10], accS[11]);
    float a6 = fmaxf(accS[12], accS[13]), a7 = fmaxf(accS[14], accS[15]);
    a0 = fmaxf(a0, a1); a2 = fmaxf(a2, a3); a4 = fmaxf(a4, a5); a6 = fmaxf(a6, a7);
    float mx = fmaxf(fmaxf(a0, a2), fmaxf(a4, a6));
    mx = fmaxf(mx, __shfl_xor(mx, 32));
    m_true = fmaxf(m_true, mx);
    const bool fold = __any(mx > m_run + SLACK);
    const float mn = fold ? fmaxf(m_run, mx) : m_run;
    float lsum = 0.0f;
    unsigned int pk[4][2];
    #pragma unroll
    for (int u = 0; u < 4; ++u) {
      const float p0 = exp2f(accS[4 * u + 0] - mn);
      const float p1 = exp2f(accS[4 * u + 1] - mn);
      const float p2 = exp2f(accS[4 * u + 2] - mn);
      const float p3 = exp2f(accS[4 * u + 3] - mn);
      lsum += (p0 + p1) + (p2 + p3);
      pk[u][0] = pkh(p0, p1);
      pk[u][1] = pkh(p2, p3);
    }
    lsum += __shfl_xor(lsum, 32);
    if (fold) {
      const float alpha = exp2f(m_run - mn);
      l_run = l_run * alpha + lsum;
      m_run = mn;
      #pragma unroll
      for (int mt = 0; mt < 4; ++mt)
        #pragma unroll
        for (int r = 0; r < 16; ++r) accO[mt][r] *= alpha;
    } else {
      l_run += lsum;
    }
    #pragma unroll
    for (int s = 0; s < 2; ++s) {
      const unsigned int s0 = pk[2 * s + (g ^ 1)][0];
      const unsigned int s1 = pk[2 * s + (g ^ 1)][1];
      const unsigned int t0 = __shfl_xor(s0, 32);
      const unsigned int t1 = __shfl_xor(s1, 32);
      union { unsigned int u[4]; h8v v; } bP;
      bP.u[0] = g ? t0 : pk[2 * s][0];
      bP.u[1] = g ? t1 : pk[2 * s][1];
      bP.u[2] = g ? pk[2 * s + 1][0] : t0;
      bP.u[3] = g ? pk[2 * s + 1][1] : t1;
      #pragma unroll
      for (int mt = 0; mt < 4; ++mt) {
        const int dr = 32 * mt + qlane;
        union { unsigned int u[4]; h8v v; } aV;
        const uint2 lo = *(const uint2*)&vsb[dr * 36 + (2 * s + g) * 8];
        const uint2 hi2 = *(const uint2*)&vsb[dr * 36 + (2 * s + g) * 8 + 4];
        aV.u[0] = lo.x; aV.u[1] = lo.y; aV.u[2] = hi2.x; aV.u[3] = hi2.y;
        accO[mt] = __builtin_amdgcn_mfma_f32_32x32x16_f16(aV.v, bP.v, accO[mt], 0, 0, 0);
      }
    }
  };

  auto LOADSTG = [&](int tile) {
    const int k0n = tile * TKF;
    #pragma unroll
    for (int i = 0; i < 2; ++i) {
      const int kr = kr0 + i * 16;
      stgK[i] = *(const uint4*)&Kg[(kgbase + k0n + kr) * ICH + kc_ * 8];
      const int idx = tid * 2 + i, dr = idx >> 2, cv = idx & 3;
      stgV[i] = *(const uint4*)&Vtg[vgbase + (size_t)dr * NPOS + k0n + cv * 8];
    }
  };
  auto WRITESTG = [&](int buf, int slot) {
    #pragma unroll
    for (int i = 0; i < 2; ++i) {
      const int kr = kr0 + i * 16;
      *(uint4*)&Ks[buf][slot * 4096 + kr * 128 + (kc_ ^ (kr & 15)) * 8] = stgK[i];
      const int idx = tid * 2 + i, dr = idx >> 2, cv = idx & 3;
      *(uint2*)&Vs[buf][slot * 4608 + dr * 36 + cv * 8]     = make_uint2(stgV[i].x, stgV[i].y);
      *(uint2*)&Vs[buf][slot * 4608 + dr * 36 + cv * 8 + 4] = make_uint2(stgV[i].z, stgV[i].w);
    }
  };

  // ---- 24 epochs: tiles {2e, 2e+1} from buf e&1; prefetch {2e+2, 2e+3} ----
  for (int e = 0; e < 24; ++e) {
    const int cur = e & 1, nb = cur ^ 1;
    LOADSTG(2 * e + 2);                       // tile A (always < 49)
    FTILE(&Ks[cur][0], &Vs[cur][0]);
    WRITESTG(nb, 0);
    const bool hasB = (2 * e + 3 < NITK);     // false only at e=23
    if (hasB) LOADSTG(2 * e + 3);
    FTILE(&Ks[cur][4096], &Vs[cur][4608]);
    if (hasB) WRITESTG(nb, 1);
    __syncthreads();
  }
  // ---- tail: tile 48 (in buf0 slot0) ----
  FTILE(&Ks[0][0], &Vs[0][0]);

  // epilogue: renormalize to true max, store f16 partial O + (m,l)
  const float scale = exp2f(m_run - m_true);
  const int ncol = n0 + 32 * wv + qlane;
  const size_t obase = (size_t)(b * KSPL + spl) * ICH * NPOS;
  #pragma unroll
  for (int mt = 0; mt < 4; ++mt)
    #pragma unroll
    for (int r = 0; r < 16; ++r) {
      const int d = 32 * mt + (r & 3) + 8 * (r >> 2) + 4 * g;
      Opart[obase + (size_t)d * NPOS + ncol] = f2h(accO[mt][r] * scale);
    }
  if (g == 0) {
    Mpart[(size_t)(b * KSPL + spl) * NPOS + ncol] = m_true;
    Lpart[(size_t)(b * KSPL + spl) * NPOS + ncol] = l_run * scale;
  }
}

// ---------------------------------------------------------------------------
// mz_kernel: fused merge + zres, MFMA. grid (N/128, C/128=2, B), 256 thr.
// ---------------------------------------------------------------------------
__global__ __launch_bounds__(256, 2)
void mz_kernel(const float* __restrict__ x,
               const float* __restrict__ Wz,
               const unsigned short* __restrict__ Opart,
               const float* __restrict__ Mpart,
               const float* __restrict__ Lpart,
               float* __restrict__ out) {
  __shared__ float4 wgt[128];
  __shared__ unsigned short Yh[128][24], Yl[128][24];
  __shared__ unsigned short Wzh[128][24], Wzl[128][24];

  const int n0 = blockIdx.x * 128;
  const int c0 = blockIdx.y * 128;
  const int b  = blockIdx.z;
  const int tid = threadIdx.x;
  const int lane = tid & 63, wv = tid >> 6;
  const int ln = lane & 31, g = lane >> 5;

  if (tid < 128) {
    const int n = n0 + tid;
    float m[4], l[4];
    #pragma unroll
    for (int s = 0; s < 4; ++s) {
      m[s] = Mpart[(size_t)(b * KSPL + s) * NPOS + n];
      l[s] = Lpart[(size_t)(b * KSPL + s) * NPOS + n];
    }
    const float M0 = fmaxf(fmaxf(m[0], m[1]), fmaxf(m[2], m[3]));
    float w[4], lt = 0.0f;
    #pragma unroll
    for (int s = 0; s < 4; ++s) { w[s] = exp2f(m[s] - M0); lt += w[s] * l[s]; }
    const float inv = 1.0f / lt;
    float4 o;
    o.x = w[0] * inv; o.y = w[1] * inv; o.z = w[2] * inv; o.w = w[3] * inv;
    wgt[tid] = o;
  }
  __syncthreads();

  const int np  = tid & 63;
  const int icg = tid >> 6;
  const float4 wsA4 = wgt[2 * np];
  const float4 wsB4 = wgt[2 * np + 1];
  const float wA[4] = {wsA4.x, wsA4.y, wsA4.z, wsA4.w};
  const float wB[4] = {wsB4.x, wsB4.y, wsB4.z, wsB4.w};
  const int wc = tid >> 1, wh = (tid & 1) * 8;
  const float* Wzrow = Wz + (size_t)(c0 + wc) * ICH + wh;
  const int cpair = wv >> 1, npair = wv & 1;

  fx16 acc[2][2];
  acc[0][0] = (fx16)(0.0f); acc[0][1] = (fx16)(0.0f);
  acc[1][0] = (fx16)(0.0f); acc[1][1] = (fx16)(0.0f);

  for (int k0 = 0; k0 < ICH; k0 += 16) {
    {
      const float4 w0 = *(const float4*)&Wzrow[k0];
      const float4 w1 = *(const float4*)&Wzrow[k0 + 4];
      const float wv8[8] = {w0.x, w0.y, w0.z, w0.w, w1.x, w1.y, w1.z, w1.w};
      unsigned int hu[4], lu[4];
      #pragma unroll
      for (int q = 0; q < 4; ++q) {
        _Float16 h0 = (_Float16)wv8[2 * q], h1 = (_Float16)wv8[2 * q + 1];
        hu[q] = (unsigned int)__builtin_bit_cast(unsigned short, h0) |
                ((unsigned int)__builtin_bit_cast(unsigned short, h1) << 16);
        lu[q] = (unsigned int)f2h(wv8[2 * q] - (float)h0) |
                ((unsigned int)f2h(wv8[2 * q + 1] - (float)h1) << 16);
      }
      *(uint4*)&Wzh[wc][wh] = make_uint4(hu[0], hu[1], hu[2], hu[3]);
      *(uint4*)&Wzl[wc][wh] = make_uint4(lu[0], lu[1], lu[2], lu[3]);
    }
    {
      unsigned short h0a[4], h1a[4], l0a[4], l1a[4];
      #pragma unroll
      for (int j = 0; j < 4; ++j) {
        const int ic = k0 + icg * 4 + j;
        float y0 = 0.0f, y1 = 0.0f;
        #pragma unroll
        for (int s = 0; s < 4; ++s) {
          const unsigned int u = *(const unsigned int*)
            &Opart[((size_t)(b * KSPL + s) * ICH + ic) * NPOS + n0 + 2 * np];
          y0 += wA[s] * h2f((unsigned short)(u & 0xffff));
          y1 += wB[s] * h2f((unsigned short)(u >> 16));
        }
        _Float16 hh0 = (_Float16)y0, hh1 = (_Float16)y1;
        h0a[j] = __builtin_bit_cast(unsigned short, hh0);
        h1a[j] = __builtin_bit_cast(unsigned short, hh1);
        l0a[j] = f2h(y0 - (float)hh0);
        l1a[j] = f2h(y1 - (float)hh1);
      }
      const int kc = icg * 4;
      *(uint2*)&Yh[2 * np][kc] = make_uint2(
        (unsigned)h0a[0] | ((unsigned)h0a[1] << 16),
        (unsigned)h0a[2] | ((unsigned)h0a[3] << 16));
      *(uint2*)&Yh[2 * np + 1][kc] = make_uint2(
        (unsigned)h1a[0] | ((unsigned)h1a[1] << 16),
        (unsigned)h1a[2] | ((unsigned)h1a[3] << 16));
      *(uint2*)&Yl[2 * np][kc] = make_uint2(
        (unsigned)l0a[0] | ((unsigned)l0a[1] << 16),
        (unsigned)l0a[2] | ((unsigned)l0a[3] << 16));
      *(uint2*)&Yl[2 * np + 1][kc] = make_uint2(
        (unsigned)l1a[0] | ((unsigned)l1a[1] << 16),
        (unsigned)l1a[2] | ((unsigned)l1a[3] << 16));
    }
    __syncthreads();

    h8v Ah[2], Al[2], Bh[2], Bl[2];
    #pragma unroll
    for (int ci = 0; ci < 2; ++ci) {
      const int cr = (cpair * 2 + ci) * 32 + ln;
      Ah[ci] = *(const h8v*)&Wzh[cr][g * 8];
      Al[ci] = *(const h8v*)&Wzl[cr][g * 8];
    }
    #pragma unroll
    for (int ni = 0; ni < 2; ++ni) {
      const int nr = (npair * 2 + ni) * 32 + ln;
      Bh[ni] = *(const h8v*)&Yh[nr][g * 8];
      Bl[ni] = *(const h8v*)&Yl[nr][g * 8];
    }
    #pragma unroll
    for (int ci = 0; ci < 2; ++ci)
      #pragma unroll
      for (int ni = 0; ni < 2; ++ni) {
        acc[ci][ni] = __builtin_amdgcn_mfma_f32_32x32x16_f16(Ah[ci], Bh[ni], acc[ci][ni], 0, 0, 0);
        acc[ci][ni] = __builtin_amdgcn_mfma_f32_32x32x16_f16(Ah[ci], Bl[ni], acc[ci][ni], 0, 0, 0);
        acc[ci][ni] = __builtin_amdgcn_mfma_f32_32x32x16_f16(Al[ci], Bh[ni], acc[ci][ni], 0, 0, 0);
      }
    __syncthreads();
  }

  #pragma unroll
  for (int ci = 0; ci < 2; ++ci)
    #pragma unroll
    for (int ni = 0; ni < 2; ++ni) {
      const int n = n0 + npair * 64 + ni * 32 + ln;
      #pragma unroll
      for (int r = 0; r < 16; ++r) {
        const int c = c0 + cpair * 64 + ci * 32 + (r & 3) + 8 * (r >> 2) + 4 * g;
        const size_t base = ((size_t)(b * CCH + c)) * NPOS + n;
        out[base] = acc[ci][ni][r] + x[base];
      }
    }
}

// ---------------------------------------------------------------------------
extern "C" void kernel_launch(void* const* d_in, const int* in_sizes, int n_in,
                              void* d_out, int out_size, void* d_ws, size_t ws_size,
                              hipStream_t stream) {
  const float* x      = (const float*)d_in[0];
  const float* Wg     = (const float*)d_in[1];
  const float* Wtheta = (const float*)d_in[2];
  const float* Wphi   = (const float*)d_in[3];
  const float* Wz     = (const float*)d_in[4];
  float* out = (float*)d_out;

  unsigned short* Qg    = (unsigned short*)d_ws;
  unsigned short* Kg    = Qg + BNIC;
  unsigned short* Vtg   = Kg + BNIC;
  unsigned short* Opart = Vtg + BNIC;                    // KSPL*BNIC ushorts
  float* Mpart = (float*)(Opart + (size_t)KSPL * BNIC);  // KSPL*B*N floats
  float* Lpart = Mpart + (size_t)KSPL * BB * NPOS;       // KSPL*B*N floats

  // Whi/Wlo overlay the Opart region: dead until flash11 writes Opart,
  // and proj_mfma (the only reader) runs before flash11.
  unsigned short* Whi = Opart;                           // 3*128*256 ushorts
  unsigned short* Wlo = Whi + 3 * 128 * 256;

  wconv<<<dim3(96), 256, 0, stream>>>(Wtheta, Wphi, Wg, Whi, Wlo);
  proj_mfma<<<dim3(NPOS / 32, BB), 256, 0, stream>>>(x, Whi, Wlo, Qg, Kg, Vtg);
  flash11 <<<dim3(BB * KSPL * NITK), 256, 0, stream>>>(Qg, Kg, Vtg, Opart, Mpart, Lpart);
  mz_kernel<<<dim3(NPOS / 128, CCH / 128, BB), 256, 0, stream>>>(x, Wz, Opart, Mpart, Lpart, out);
}

// Round 9
// 311.044 us; speedup vs baseline: 1.0560x; 1.0560x over previous
//
#include <hip/hip_runtime.h>
#include <cstdint>

// SpacetimeNonLocalBlock: B=4, C=256, T*H*W=N=6272, IC=128.
// R16: flash is wave-starved (R8/R10/R11/R12/R15 all land 186-212us at
// ~3 blocks/CU; barrier/memory/pipeline theories falsified). Fix: KSPL 4->7
// (6272=7*896, NITK=28) -> grid 784->1372 blocks = 5.36/CU, ~75% more waves
// to hide the serial QK->softmax->PV chain. flash body = EXACT flash10,
// templated on KS; mz templated (7-way merge). ws_size-gated: falls back to
// KS=4 (R14 best path) if workspace too small. proj_mfma = R15 keeper
// (c-step 32, conflict-free 40-stride; non-flash improved ~12us in R15).
// flash11's 2-tile epochs reverted (LDS 76KB cut blocks/CU, conflicts 6M).

#define BB   4
#define CCH  256
#define NPOS 6272
#define ICH  128
#define BNIC ((size_t)BB * NPOS * ICH)
#define TKF  32
#define SLACK 12.0f

typedef __attribute__((ext_vector_type(8)))  _Float16 h8v;  // 8 f16 MFMA frag
typedef __attribute__((ext_vector_type(16))) float fx16;    // 32x32 acc

__device__ __forceinline__ unsigned short f2h(float f) {
  _Float16 h = (_Float16)f;
  return __builtin_bit_cast(unsigned short, h);
}
__device__ __forceinline__ unsigned int pkh(float lo, float hi) {
  return __builtin_bit_cast(unsigned int, __builtin_amdgcn_cvt_pkrtz(lo, hi));
}
__device__ __forceinline__ float h2f(unsigned short u) {
  return (float)__builtin_bit_cast(_Float16, u);
}

// ---------------------------------------------------------------------------
// wconv: [Wtheta;Wphi;Wg] (3x128x256 f32) -> Whi/Wlo f16 split. grid 96.
// ---------------------------------------------------------------------------
__global__ __launch_bounds__(256, 1)
void wconv(const float* __restrict__ Wtheta, const float* __restrict__ Wphi,
           const float* __restrict__ Wg,
           unsigned short* __restrict__ Whi, unsigned short* __restrict__ Wlo) {
  const int idx4 = (blockIdx.x * 256 + threadIdx.x) * 4;   // [0, 98304) step 4
  const int p = idx4 >> 15;                                // 0,1,2 (128*256=32768)
  const float* W = (p == 0) ? Wtheta : (p == 1) ? Wphi : Wg;
  const float4 v = *(const float4*)&W[idx4 - (p << 15)];
  const float vv[4] = {v.x, v.y, v.z, v.w};
  ushort4 h, l;
  unsigned short* hp = (unsigned short*)&h;
  unsigned short* lp = (unsigned short*)&l;
  #pragma unroll
  for (int q = 0; q < 4; ++q) {
    _Float16 hh = (_Float16)vv[q];
    hp[q] = __builtin_bit_cast(unsigned short, hh);
    lp[q] = f2h(vv[q] - (float)hh);
  }
  *(ushort4*)&Whi[idx4] = h;
  *(ushort4*)&Wlo[idx4] = l;
}

// ---------------------------------------------------------------------------
// proj_mfma (R15 keeper): grid (N/32, B), 256 thr. c-step 32 per epoch,
// x staged f16 hi/lo [32n][40c-stride] (b128 reads conflict-free).
// ---------------------------------------------------------------------------
__global__ __launch_bounds__(256, 2)
void proj_mfma(const float* __restrict__ x,
               const unsigned short* __restrict__ Whi,
               const unsigned short* __restrict__ Wlo,
               unsigned short* __restrict__ Qg,
               unsigned short* __restrict__ Kg,
               unsigned short* __restrict__ Vtg) {
  __shared__ unsigned short Xhi[32][40];
  __shared__ unsigned short Xlo[32][40];
  const int n0 = blockIdx.x * 32;
  const int b  = blockIdx.y;
  const int tid = threadIdx.x;
  const int lane = tid & 63, wv = tid >> 6;
  const int ln = lane & 31, g = lane >> 5;

  fx16 acc[3];
  acc[0] = (fx16)(0.0f); acc[1] = (fx16)(0.0f); acc[2] = (fx16)(0.0f);

  const int sn = tid & 31, cq = (tid >> 5) * 4;
  const float* xp = x + ((size_t)b * CCH + cq) * NPOS + n0 + sn;

  float pv[4];
  #pragma unroll
  for (int q = 0; q < 4; ++q) pv[q] = xp[(size_t)q * NPOS];

  for (int c0 = 0; c0 < CCH; c0 += 32) {
    {
      ushort4 h4, l4;
      unsigned short* hp = (unsigned short*)&h4;
      unsigned short* lp = (unsigned short*)&l4;
      #pragma unroll
      for (int q = 0; q < 4; ++q) {
        _Float16 hh = (_Float16)pv[q];
        hp[q] = __builtin_bit_cast(unsigned short, hh);
        lp[q] = f2h(pv[q] - (float)hh);
      }
      *(ushort4*)&Xhi[sn][cq] = h4;
      *(ushort4*)&Xlo[sn][cq] = l4;
    }
    if (c0 + 32 < CCH) {
      #pragma unroll
      for (int q = 0; q < 4; ++q) pv[q] = xp[(size_t)(c0 + 32 + q) * NPOS];
    }
    __syncthreads();
    #pragma unroll
    for (int kc = 0; kc < 2; ++kc) {
      const h8v bxh = *(const h8v*)&Xhi[ln][kc * 16 + g * 8];
      const h8v bxl = *(const h8v*)&Xlo[ln][kc * 16 + g * 8];
      #pragma unroll
      for (int t = 0; t < 3; ++t) {
        const int T = wv * 3 + t;
        const size_t wb = ((size_t)(T * 32 + ln)) * CCH + c0 + kc * 16 + g * 8;
        const h8v ah = *(const h8v*)&Whi[wb];
        const h8v al = *(const h8v*)&Wlo[wb];
        acc[t] = __builtin_amdgcn_mfma_f32_32x32x16_f16(ah, bxh, acc[t], 0, 0, 0);
        acc[t] = __builtin_amdgcn_mfma_f32_32x32x16_f16(ah, bxl, acc[t], 0, 0, 0);
        acc[t] = __builtin_amdgcn_mfma_f32_32x32x16_f16(al, bxh, acc[t], 0, 0, 0);
      }
    }
    __syncthreads();
  }

  const float LOG2E = 1.4426950408889634f;
  const int n = n0 + ln;
  #pragma unroll
  for (int t = 0; t < 3; ++t) {
    const int T = wv * 3 + t;
    const int p = T >> 2;
    const int ot = (T & 3) * 32;
    if (p < 2) {
      unsigned short* Out = (p == 0) ? Qg : Kg;
      const float scl = (p == 0) ? LOG2E : 1.0f;
      #pragma unroll
      for (int q = 0; q < 4; ++q) {
        ushort4 v;
        v.x = f2h(acc[t][4 * q + 0] * scl);
        v.y = f2h(acc[t][4 * q + 1] * scl);
        v.z = f2h(acc[t][4 * q + 2] * scl);
        v.w = f2h(acc[t][4 * q + 3] * scl);
        *(ushort4*)&Out[((size_t)b * NPOS + n) * ICH + ot + 8 * q + 4 * g] = v;
      }
    } else {
      #pragma unroll
      for (int r = 0; r < 16; ++r) {
        const int o = ot + (r & 3) + 8 * (r >> 2) + 4 * g;
        Vtg[((size_t)b * ICH + o) * NPOS + n] = f2h(acc[t][r]);
      }
    }
  }
}

// ---------------------------------------------------------------------------
// flash_t<KS>: EXACT flash10 body; grid (49, KS, B). KLEN = N/KS,
// NIT = KLEN/32. LDS 34 KB: Ks[2][32x128] 4-bit swz, Vs[2][128x36].
// ---------------------------------------------------------------------------
template <int KS>
__global__ __launch_bounds__(256, 2)
void flash_t(const unsigned short* __restrict__ Qg,
             const unsigned short* __restrict__ Kg,
             const unsigned short* __restrict__ Vtg,
             unsigned short* __restrict__ Opart,
             float* __restrict__ Mpart,
             float* __restrict__ Lpart) {
  constexpr int KLEN = NPOS / KS;
  constexpr int NIT  = KLEN / TKF;
  __shared__ unsigned short Ks[2][TKF * 128];
  __shared__ unsigned short Vs[2][128 * 36];

  const int b   = blockIdx.z;
  const int spl = blockIdx.y;
  const int n0  = blockIdx.x * 128;
  const int kb  = spl * KLEN;
  const int tid = threadIdx.x;
  const int lane = tid & 63, wv = tid >> 6;
  const int qlane = lane & 31, g = lane >> 5;
  const int swz = qlane & 15;

  h8v qf[8];
  {
    const size_t qbase = ((size_t)b * NPOS + n0 + 32 * wv + qlane) * ICH;
    #pragma unroll
    for (int cs = 0; cs < 8; ++cs)
      qf[cs] = *(const h8v*)&Qg[qbase + cs * 16 + g * 8];
  }

  {
    #pragma unroll
    for (int i = 0; i < 2; ++i) {
      const int kr = (tid >> 4) + i * 16, c = tid & 15;
      const uint4 v = *(const uint4*)&Kg[((size_t)b * NPOS + kb + kr) * ICH + c * 8];
      *(uint4*)&Ks[0][kr * 128 + (c ^ (kr & 15)) * 8] = v;
      const int idx = tid * 2 + i, dr = idx >> 2, cv = idx & 3;
      const uint4 w = *(const uint4*)&Vtg[((size_t)b * ICH + dr) * NPOS + kb + cv * 8];
      *(uint2*)&Vs[0][dr * 36 + cv * 8]     = make_uint2(w.x, w.y);
      *(uint2*)&Vs[0][dr * 36 + cv * 8 + 4] = make_uint2(w.z, w.w);
    }
  }
  __syncthreads();

  float m_run = -1e30f, m_true = -1e30f, l_run = 0.0f;
  fx16 accO[4];
  #pragma unroll
  for (int mt = 0; mt < 4; ++mt) accO[mt] = (fx16)(0.0f);

  uint4 stgK[2], stgV[2];

  for (int it = 0; it < NIT; ++it) {
    const int cur = it & 1;
    const bool pre = (it + 1 < NIT);
    if (pre) {
      const int k0n = kb + (it + 1) * TKF;
      #pragma unroll
      for (int i = 0; i < 2; ++i) {
        const int kr = (tid >> 4) + i * 16;
        stgK[i] = *(const uint4*)&Kg[((size_t)b * NPOS + k0n + kr) * ICH + (tid & 15) * 8];
        const int idx = tid * 2 + i, dr = idx >> 2, cv = idx & 3;
        stgV[i] = *(const uint4*)&Vtg[((size_t)b * ICH + dr) * NPOS + k0n + cv * 8];
      }
    }

    // ---- S^T = K . Q^T ----
    fx16 accS = (fx16)(0.0f);
    #pragma unroll
    for (int cs = 0; cs < 8; ++cs) {
      const h8v aK = *(const h8v*)&Ks[cur][qlane * 128 + ((2 * cs + g) ^ swz) * 8];
      accS = __builtin_amdgcn_mfma_f32_32x32x16_f16(aK, qf[cs], accS, 0, 0, 0);
    }

    // ---- slack-fold online softmax (log2 domain), tree max ----
    float a0 = fmaxf(accS[0], accS[1]),   a1 = fmaxf(accS[2], accS[3]);
    float a2 = fmaxf(accS[4], accS[5]),   a3 = fmaxf(accS[6], accS[7]);
    float a4 = fmaxf(accS[8], accS[9]),   a5 = fmaxf(accS[10], accS[11]);
    float a6 = fmaxf(accS[12], accS[13]), a7 = fmaxf(accS[14], accS[15]);
    a0 = fmaxf(a0, a1); a2 = fmaxf(a2, a3); a4 = fmaxf(a4, a5); a6 = fmaxf(a6, a7);
    float mx = fmaxf(fmaxf(a0, a2), fmaxf(a4, a6));
    mx = fmaxf(mx, __shfl_xor(mx, 32));
    m_true = fmaxf(m_true, mx);
    const bool fold = __any(mx > m_run + SLACK);
    const float mn = fold ? fmaxf(m_run, mx) : m_run;
    float lsum = 0.0f;
    unsigned int pk[4][2];
    #pragma unroll
    for (int u = 0; u < 4; ++u) {
      const float p0 = exp2f(accS[4 * u + 0] - mn);
      const float p1 = exp2f(accS[4 * u + 1] - mn);
      const float p2 = exp2f(accS[4 * u + 2] - mn);
      const float p3 = exp2f(accS[4 * u + 3] - mn);
      lsum += (p0 + p1) + (p2 + p3);
      pk[u][0] = pkh(p0, p1);
      pk[u][1] = pkh(p2, p3);
    }
    lsum += __shfl_xor(lsum, 32);
    if (fold) {
      const float alpha = exp2f(m_run - mn);
      l_run = l_run * alpha + lsum;
      m_run = mn;
      #pragma unroll
      for (int mt = 0; mt < 4; ++mt)
        #pragma unroll
        for (int r = 0; r < 16; ++r) accO[mt][r] *= alpha;
    } else {
      l_run += lsum;
    }

    // ---- PV: O^T += V^T . P^T ----
    #pragma unroll
    for (int s = 0; s < 2; ++s) {
      const unsigned int s0 = pk[2 * s + (g ^ 1)][0];
      const unsigned int s1 = pk[2 * s + (g ^ 1)][1];
      const unsigned int t0 = __shfl_xor(s0, 32);
      const unsigned int t1 = __shfl_xor(s1, 32);
      union { unsigned int u[4]; h8v v; } bP;
      bP.u[0] = g ? t0 : pk[2 * s][0];
      bP.u[1] = g ? t1 : pk[2 * s][1];
      bP.u[2] = g ? pk[2 * s + 1][0] : t0;
      bP.u[3] = g ? pk[2 * s + 1][1] : t1;
      #pragma unroll
      for (int mt = 0; mt < 4; ++mt) {
        const int dr = 32 * mt + qlane;
        union { unsigned int u[4]; h8v v; } aV;
        const uint2 lo = *(const uint2*)&Vs[cur][dr * 36 + (2 * s + g) * 8];
        const uint2 hi = *(const uint2*)&Vs[cur][dr * 36 + (2 * s + g) * 8 + 4];
        aV.u[0] = lo.x; aV.u[1] = lo.y; aV.u[2] = hi.x; aV.u[3] = hi.y;
        accO[mt] = __builtin_amdgcn_mfma_f32_32x32x16_f16(aV.v, bP.v, accO[mt], 0, 0, 0);
      }
    }

    if (pre) {
      const int nb = cur ^ 1;
      #pragma unroll
      for (int i = 0; i < 2; ++i) {
        const int kr = (tid >> 4) + i * 16;
        *(uint4*)&Ks[nb][kr * 128 + ((tid & 15) ^ (kr & 15)) * 8] = stgK[i];
        const int idx = tid * 2 + i, dr = idx >> 2, cv = idx & 3;
        *(uint2*)&Vs[nb][dr * 36 + cv * 8]     = make_uint2(stgV[i].x, stgV[i].y);
        *(uint2*)&Vs[nb][dr * 36 + cv * 8 + 4] = make_uint2(stgV[i].z, stgV[i].w);
      }
    }
    __syncthreads();
  }

  // epilogue: renormalize to true max, store f16 partial O + (m,l)
  const float scale = exp2f(m_run - m_true);
  const int ncol = n0 + 32 * wv + qlane;
  const size_t obase = (size_t)(b * KS + spl) * ICH * NPOS;
  #pragma unroll
  for (int mt = 0; mt < 4; ++mt)
    #pragma unroll
    for (int r = 0; r < 16; ++r) {
      const int d = 32 * mt + (r & 3) + 8 * (r >> 2) + 4 * g;
      Opart[obase + (size_t)d * NPOS + ncol] = f2h(accO[mt][r] * scale);
    }
  if (g == 0) {
    Mpart[(size_t)(b * KS + spl) * NPOS + ncol] = m_true;
    Lpart[(size_t)(b * KS + spl) * NPOS + ncol] = l_run * scale;
  }
}

// ---------------------------------------------------------------------------
// mz_t<KS>: fused merge + zres, MFMA. grid (N/128, C/128=2, B), 256 thr.
// ---------------------------------------------------------------------------
template <int KS>
__global__ __launch_bounds__(256, 2)
void mz_t(const float* __restrict__ x,
          const float* __restrict__ Wz,
          const unsigned short* __restrict__ Opart,
          const float* __restrict__ Mpart,
          const float* __restrict__ Lpart,
          float* __restrict__ out) {
  __shared__ float wgt[128][8];
  __shared__ unsigned short Yh[128][24], Yl[128][24];
  __shared__ unsigned short Wzh[128][24], Wzl[128][24];

  const int n0 = blockIdx.x * 128;
  const int c0 = blockIdx.y * 128;
  const int b  = blockIdx.z;
  const int tid = threadIdx.x;
  const int lane = tid & 63, wv = tid >> 6;
  const int ln = lane & 31, g = lane >> 5;

  if (tid < 128) {
    const int n = n0 + tid;
    float m[KS], l[KS];
    float M0 = -1e30f;
    #pragma unroll
    for (int s = 0; s < KS; ++s) {
      m[s] = Mpart[(size_t)(b * KS + s) * NPOS + n];
      l[s] = Lpart[(size_t)(b * KS + s) * NPOS + n];
      M0 = fmaxf(M0, m[s]);
    }
    float w[KS], lt = 0.0f;
    #pragma unroll
    for (int s = 0; s < KS; ++s) { w[s] = exp2f(m[s] - M0); lt += w[s] * l[s]; }
    const float inv = 1.0f / lt;
    #pragma unroll
    for (int s = 0; s < KS; ++s) wgt[tid][s] = w[s] * inv;
  }
  __syncthreads();

  const int np  = tid & 63;
  const int icg = tid >> 6;
  float wA[KS], wB[KS];
  #pragma unroll
  for (int s = 0; s < KS; ++s) { wA[s] = wgt[2 * np][s]; wB[s] = wgt[2 * np + 1][s]; }
  const int wc = tid >> 1, wh = (tid & 1) * 8;
  const float* Wzrow = Wz + (size_t)(c0 + wc) * ICH + wh;
  const int cpair = wv >> 1, npair = wv & 1;

  fx16 acc[2][2];
  acc[0][0] = (fx16)(0.0f); acc[0][1] = (fx16)(0.0f);
  acc[1][0] = (fx16)(0.0f); acc[1][1] = (fx16)(0.0f);

  for (int k0 = 0; k0 < ICH; k0 += 16) {
    {
      const float4 w0 = *(const float4*)&Wzrow[k0];
      const float4 w1 = *(const float4*)&Wzrow[k0 + 4];
      const float wv8[8] = {w0.x, w0.y, w0.z, w0.w, w1.x, w1.y, w1.z, w1.w};
      unsigned int hu[4], lu[4];
      #pragma unroll
      for (int q = 0; q < 4; ++q) {
        _Float16 h0 = (_Float16)wv8[2 * q], h1 = (_Float16)wv8[2 * q + 1];
        hu[q] = (unsigned int)__builtin_bit_cast(unsigned short, h0) |
                ((unsigned int)__builtin_bit_cast(unsigned short, h1) << 16);
        lu[q] = (unsigned int)f2h(wv8[2 * q] - (float)h0) |
                ((unsigned int)f2h(wv8[2 * q + 1] - (float)h1) << 16);
      }
      *(uint4*)&Wzh[wc][wh] = make_uint4(hu[0], hu[1], hu[2], hu[3]);
      *(uint4*)&Wzl[wc][wh] = make_uint4(lu[0], lu[1], lu[2], lu[3]);
    }
    {
      unsigned short h0a[4], h1a[4], l0a[4], l1a[4];
      #pragma unroll
      for (int j = 0; j < 4; ++j) {
        const int ic = k0 + icg * 4 + j;
        float y0 = 0.0f, y1 = 0.0f;
        #pragma unroll
        for (int s = 0; s < KS; ++s) {
          const unsigned int u = *(const unsigned int*)
            &Opart[((size_t)(b * KS + s) * ICH + ic) * NPOS + n0 + 2 * np];
          y0 += wA[s] * h2f((unsigned short)(u & 0xffff));
          y1 += wB[s] * h2f((unsigned short)(u >> 16));
        }
        _Float16 hh0 = (_Float16)y0, hh1 = (_Float16)y1;
        h0a[j] = __builtin_bit_cast(unsigned short, hh0);
        h1a[j] = __builtin_bit_cast(unsigned short, hh1);
        l0a[j] = f2h(y0 - (float)hh0);
        l1a[j] = f2h(y1 - (float)hh1);
      }
      const int kc = icg * 4;
      *(uint2*)&Yh[2 * np][kc] = make_uint2(
        (unsigned)h0a[0] | ((unsigned)h0a[1] << 16),
        (unsigned)h0a[2] | ((unsigned)h0a[3] << 16));
      *(uint2*)&Yh[2 * np + 1][kc] = make_uint2(
        (unsigned)h1a[0] | ((unsigned)h1a[1] << 16),
        (unsigned)h1a[2] | ((unsigned)h1a[3] << 16));
      *(uint2*)&Yl[2 * np][kc] = make_uint2(
        (unsigned)l0a[0] | ((unsigned)l0a[1] << 16),
        (unsigned)l0a[2] | ((unsigned)l0a[3] << 16));
      *(uint2*)&Yl[2 * np + 1][kc] = make_uint2(
        (unsigned)l1a[0] | ((unsigned)l1a[1] << 16),
        (unsigned)l1a[2] | ((unsigned)l1a[3] << 16));
    }
    __syncthreads();

    h8v Ah[2], Al[2], Bh[2], Bl[2];
    #pragma unroll
    for (int ci = 0; ci < 2; ++ci) {
      const int cr = (cpair * 2 + ci) * 32 + ln;
      Ah[ci] = *(const h8v*)&Wzh[cr][g * 8];
      Al[ci] = *(const h8v*)&Wzl[cr][g * 8];
    }
    #pragma unroll
    for (int ni = 0; ni < 2; ++ni) {
      const int nr = (npair * 2 + ni) * 32 + ln;
      Bh[ni] = *(const h8v*)&Yh[nr][g * 8];
      Bl[ni] = *(const h8v*)&Yl[nr][g * 8];
    }
    #pragma unroll
    for (int ci = 0; ci < 2; ++ci)
      #pragma unroll
      for (int ni = 0; ni < 2; ++ni) {
        acc[ci][ni] = __builtin_amdgcn_mfma_f32_32x32x16_f16(Ah[ci], Bh[ni], acc[ci][ni], 0, 0, 0);
        acc[ci][ni] = __builtin_amdgcn_mfma_f32_32x32x16_f16(Ah[ci], Bl[ni], acc[ci][ni], 0, 0, 0);
        acc[ci][ni] = __builtin_amdgcn_mfma_f32_32x32x16_f16(Al[ci], Bh[ni], acc[ci][ni], 0, 0, 0);
      }
    __syncthreads();
  }

  #pragma unroll
  for (int ci = 0; ci < 2; ++ci)
    #pragma unroll
    for (int ni = 0; ni < 2; ++ni) {
      const int n = n0 + npair * 64 + ni * 32 + ln;
      #pragma unroll
      for (int r = 0; r < 16; ++r) {
        const int c = c0 + cpair * 64 + ci * 32 + (r & 3) + 8 * (r >> 2) + 4 * g;
        const size_t base = ((size_t)(b * CCH + c)) * NPOS + n;
        out[base] = acc[ci][ni][r] + x[base];
      }
    }
}

// ---------------------------------------------------------------------------
extern "C" void kernel_launch(void* const* d_in, const int* in_sizes, int n_in,
                              void* d_out, int out_size, void* d_ws, size_t ws_size,
                              hipStream_t stream) {
  const float* x      = (const float*)d_in[0];
  const float* Wg     = (const float*)d_in[1];
  const float* Wtheta = (const float*)d_in[2];
  const float* Wphi   = (const float*)d_in[3];
  const float* Wz     = (const float*)d_in[4];
  float* out = (float*)d_out;

  unsigned short* Qg    = (unsigned short*)d_ws;
  unsigned short* Kg    = Qg + BNIC;
  unsigned short* Vtg   = Kg + BNIC;
  unsigned short* Opart = Vtg + BNIC;

  // Whi/Wlo overlay the Opart region (dead until flash writes it).
  unsigned short* Whi = Opart;                           // 3*128*256 ushorts
  unsigned short* Wlo = Whi + 3 * 128 * 256;

  wconv<<<dim3(96), 256, 0, stream>>>(Wtheta, Wphi, Wg, Whi, Wlo);
  proj_mfma<<<dim3(NPOS / 32, BB), 256, 0, stream>>>(x, Whi, Wlo, Qg, Kg, Vtg);

  const size_t need7 = (3 + 7) * BNIC * 2 + (size_t)2 * 7 * BB * NPOS * 4;
  if (ws_size >= need7) {
    constexpr int KS = 7;
    float* Mpart = (float*)(Opart + (size_t)KS * BNIC);
    float* Lpart = Mpart + (size_t)KS * BB * NPOS;
    flash_t<KS><<<dim3(NPOS / 128, KS, BB), 256, 0, stream>>>(Qg, Kg, Vtg, Opart, Mpart, Lpart);
    mz_t<KS><<<dim3(NPOS / 128, CCH / 128, BB), 256, 0, stream>>>(x, Wz, Opart, Mpart, Lpart, out);
  } else {
    constexpr int KS = 4;
    float* Mpart = (float*)(Opart + (size_t)KS * BNIC);
    float* Lpart = Mpart + (size_t)KS * BB * NPOS;
    flash_t<KS><<<dim3(NPOS / 128, KS, BB), 256, 0, stream>>>(Qg, Kg, Vtg, Opart, Mpart, Lpart);
    mz_t<KS><<<dim3(NPOS / 128, CCH / 128, BB), 256, 0, stream>>>(x, Wz, Opart, Mpart, Lpart, out);
  }
}

// Round 10
// 295.822 us; speedup vs baseline: 1.1103x; 1.0515x over previous
//
#include <hip/hip_runtime.h>
#include <cstdint>

// SpacetimeNonLocalBlock: B=4, C=256, T*H*W=N=6272, IC=128.
// R17: (1) flash_t __launch_bounds__ (256,2)->(256,3): 148 unified regs x3
// waves = 444 <= 512/SIMD, LDS 3x34=102 <= 160KB -> 3 blocks/CU possible;
// R16 showed occupancy stuck at 2 blocks/CU (25%) with the (256,2) bound.
// KS=7 kept (R16: flash 186->157us, MfmaUtil 18.5->22.8 - wave-starvation
// theory confirmed). (2) mz_t n-tile 128->64: grid 392->784 blocks (3/CU),
// per-thread Opart loads halved, acc 64->32 AGPR - mz was latency-bound at
// 1.5 blocks/CU. Bodies otherwise verbatim (flash10 core, R15 proj keeper).

#define BB   4
#define CCH  256
#define NPOS 6272
#define ICH  128
#define BNIC ((size_t)BB * NPOS * ICH)
#define TKF  32
#define SLACK 12.0f

typedef __attribute__((ext_vector_type(8)))  _Float16 h8v;  // 8 f16 MFMA frag
typedef __attribute__((ext_vector_type(16))) float fx16;    // 32x32 acc

__device__ __forceinline__ unsigned short f2h(float f) {
  _Float16 h = (_Float16)f;
  return __builtin_bit_cast(unsigned short, h);
}
__device__ __forceinline__ unsigned int pkh(float lo, float hi) {
  return __builtin_bit_cast(unsigned int, __builtin_amdgcn_cvt_pkrtz(lo, hi));
}
__device__ __forceinline__ float h2f(unsigned short u) {
  return (float)__builtin_bit_cast(_Float16, u);
}

// ---------------------------------------------------------------------------
// wconv: [Wtheta;Wphi;Wg] (3x128x256 f32) -> Whi/Wlo f16 split. grid 96.
// ---------------------------------------------------------------------------
__global__ __launch_bounds__(256, 1)
void wconv(const float* __restrict__ Wtheta, const float* __restrict__ Wphi,
           const float* __restrict__ Wg,
           unsigned short* __restrict__ Whi, unsigned short* __restrict__ Wlo) {
  const int idx4 = (blockIdx.x * 256 + threadIdx.x) * 4;   // [0, 98304) step 4
  const int p = idx4 >> 15;                                // 0,1,2 (128*256=32768)
  const float* W = (p == 0) ? Wtheta : (p == 1) ? Wphi : Wg;
  const float4 v = *(const float4*)&W[idx4 - (p << 15)];
  const float vv[4] = {v.x, v.y, v.z, v.w};
  ushort4 h, l;
  unsigned short* hp = (unsigned short*)&h;
  unsigned short* lp = (unsigned short*)&l;
  #pragma unroll
  for (int q = 0; q < 4; ++q) {
    _Float16 hh = (_Float16)vv[q];
    hp[q] = __builtin_bit_cast(unsigned short, hh);
    lp[q] = f2h(vv[q] - (float)hh);
  }
  *(ushort4*)&Whi[idx4] = h;
  *(ushort4*)&Wlo[idx4] = l;
}

// ---------------------------------------------------------------------------
// proj_mfma (R15 keeper): grid (N/32, B), 256 thr. c-step 32 per epoch,
// x staged f16 hi/lo [32n][40c-stride] (b128 reads conflict-free).
// ---------------------------------------------------------------------------
__global__ __launch_bounds__(256, 2)
void proj_mfma(const float* __restrict__ x,
               const unsigned short* __restrict__ Whi,
               const unsigned short* __restrict__ Wlo,
               unsigned short* __restrict__ Qg,
               unsigned short* __restrict__ Kg,
               unsigned short* __restrict__ Vtg) {
  __shared__ unsigned short Xhi[32][40];
  __shared__ unsigned short Xlo[32][40];
  const int n0 = blockIdx.x * 32;
  const int b  = blockIdx.y;
  const int tid = threadIdx.x;
  const int lane = tid & 63, wv = tid >> 6;
  const int ln = lane & 31, g = lane >> 5;

  fx16 acc[3];
  acc[0] = (fx16)(0.0f); acc[1] = (fx16)(0.0f); acc[2] = (fx16)(0.0f);

  const int sn = tid & 31, cq = (tid >> 5) * 4;
  const float* xp = x + ((size_t)b * CCH + cq) * NPOS + n0 + sn;

  float pv[4];
  #pragma unroll
  for (int q = 0; q < 4; ++q) pv[q] = xp[(size_t)q * NPOS];

  for (int c0 = 0; c0 < CCH; c0 += 32) {
    {
      ushort4 h4, l4;
      unsigned short* hp = (unsigned short*)&h4;
      unsigned short* lp = (unsigned short*)&l4;
      #pragma unroll
      for (int q = 0; q < 4; ++q) {
        _Float16 hh = (_Float16)pv[q];
        hp[q] = __builtin_bit_cast(unsigned short, hh);
        lp[q] = f2h(pv[q] - (float)hh);
      }
      *(ushort4*)&Xhi[sn][cq] = h4;
      *(ushort4*)&Xlo[sn][cq] = l4;
    }
    if (c0 + 32 < CCH) {
      #pragma unroll
      for (int q = 0; q < 4; ++q) pv[q] = xp[(size_t)(c0 + 32 + q) * NPOS];
    }
    __syncthreads();
    #pragma unroll
    for (int kc = 0; kc < 2; ++kc) {
      const h8v bxh = *(const h8v*)&Xhi[ln][kc * 16 + g * 8];
      const h8v bxl = *(const h8v*)&Xlo[ln][kc * 16 + g * 8];
      #pragma unroll
      for (int t = 0; t < 3; ++t) {
        const int T = wv * 3 + t;
        const size_t wb = ((size_t)(T * 32 + ln)) * CCH + c0 + kc * 16 + g * 8;
        const h8v ah = *(const h8v*)&Whi[wb];
        const h8v al = *(const h8v*)&Wlo[wb];
        acc[t] = __builtin_amdgcn_mfma_f32_32x32x16_f16(ah, bxh, acc[t], 0, 0, 0);
        acc[t] = __builtin_amdgcn_mfma_f32_32x32x16_f16(ah, bxl, acc[t], 0, 0, 0);
        acc[t] = __builtin_amdgcn_mfma_f32_32x32x16_f16(al, bxh, acc[t], 0, 0, 0);
      }
    }
    __syncthreads();
  }

  const float LOG2E = 1.4426950408889634f;
  const int n = n0 + ln;
  #pragma unroll
  for (int t = 0; t < 3; ++t) {
    const int T = wv * 3 + t;
    const int p = T >> 2;
    const int ot = (T & 3) * 32;
    if (p < 2) {
      unsigned short* Out = (p == 0) ? Qg : Kg;
      const float scl = (p == 0) ? LOG2E : 1.0f;
      #pragma unroll
      for (int q = 0; q < 4; ++q) {
        ushort4 v;
        v.x = f2h(acc[t][4 * q + 0] * scl);
        v.y = f2h(acc[t][4 * q + 1] * scl);
        v.z = f2h(acc[t][4 * q + 2] * scl);
        v.w = f2h(acc[t][4 * q + 3] * scl);
        *(ushort4*)&Out[((size_t)b * NPOS + n) * ICH + ot + 8 * q + 4 * g] = v;
      }
    } else {
      #pragma unroll
      for (int r = 0; r < 16; ++r) {
        const int o = ot + (r & 3) + 8 * (r >> 2) + 4 * g;
        Vtg[((size_t)b * ICH + o) * NPOS + n] = f2h(acc[t][r]);
      }
    }
  }
}

// ---------------------------------------------------------------------------
// flash_t<KS>: EXACT flash10 body; grid (49, KS, B). KLEN = N/KS,
// NIT = KLEN/32. LDS 34 KB. launch_bounds (256,3): 3 blocks/CU target.
// ---------------------------------------------------------------------------
template <int KS>
__global__ __launch_bounds__(256, 3)
void flash_t(const unsigned short* __restrict__ Qg,
             const unsigned short* __restrict__ Kg,
             const unsigned short* __restrict__ Vtg,
             unsigned short* __restrict__ Opart,
             float* __restrict__ Mpart,
             float* __restrict__ Lpart) {
  constexpr int KLEN = NPOS / KS;
  constexpr int NIT  = KLEN / TKF;
  __shared__ unsigned short Ks[2][TKF * 128];
  __shared__ unsigned short Vs[2][128 * 36];

  const int b   = blockIdx.z;
  const int spl = blockIdx.y;
  const int n0  = blockIdx.x * 128;
  const int kb  = spl * KLEN;
  const int tid = threadIdx.x;
  const int lane = tid & 63, wv = tid >> 6;
  const int qlane = lane & 31, g = lane >> 5;
  const int swz = qlane & 15;

  h8v qf[8];
  {
    const size_t qbase = ((size_t)b * NPOS + n0 + 32 * wv + qlane) * ICH;
    #pragma unroll
    for (int cs = 0; cs < 8; ++cs)
      qf[cs] = *(const h8v*)&Qg[qbase + cs * 16 + g * 8];
  }

  {
    #pragma unroll
    for (int i = 0; i < 2; ++i) {
      const int kr = (tid >> 4) + i * 16, c = tid & 15;
      const uint4 v = *(const uint4*)&Kg[((size_t)b * NPOS + kb + kr) * ICH + c * 8];
      *(uint4*)&Ks[0][kr * 128 + (c ^ (kr & 15)) * 8] = v;
      const int idx = tid * 2 + i, dr = idx >> 2, cv = idx & 3;
      const uint4 w = *(const uint4*)&Vtg[((size_t)b * ICH + dr) * NPOS + kb + cv * 8];
      *(uint2*)&Vs[0][dr * 36 + cv * 8]     = make_uint2(w.x, w.y);
      *(uint2*)&Vs[0][dr * 36 + cv * 8 + 4] = make_uint2(w.z, w.w);
    }
  }
  __syncthreads();

  float m_run = -1e30f, m_true = -1e30f, l_run = 0.0f;
  fx16 accO[4];
  #pragma unroll
  for (int mt = 0; mt < 4; ++mt) accO[mt] = (fx16)(0.0f);

  uint4 stgK[2], stgV[2];

  for (int it = 0; it < NIT; ++it) {
    const int cur = it & 1;
    const bool pre = (it + 1 < NIT);
    if (pre) {
      const int k0n = kb + (it + 1) * TKF;
      #pragma unroll
      for (int i = 0; i < 2; ++i) {
        const int kr = (tid >> 4) + i * 16;
        stgK[i] = *(const uint4*)&Kg[((size_t)b * NPOS + k0n + kr) * ICH + (tid & 15) * 8];
        const int idx = tid * 2 + i, dr = idx >> 2, cv = idx & 3;
        stgV[i] = *(const uint4*)&Vtg[((size_t)b * ICH + dr) * NPOS + k0n + cv * 8];
      }
    }

    // ---- S^T = K . Q^T ----
    fx16 accS = (fx16)(0.0f);
    #pragma unroll
    for (int cs = 0; cs < 8; ++cs) {
      const h8v aK = *(const h8v*)&Ks[cur][qlane * 128 + ((2 * cs + g) ^ swz) * 8];
      accS = __builtin_amdgcn_mfma_f32_32x32x16_f16(aK, qf[cs], accS, 0, 0, 0);
    }

    // ---- slack-fold online softmax (log2 domain), tree max ----
    float a0 = fmaxf(accS[0], accS[1]),   a1 = fmaxf(accS[2], accS[3]);
    float a2 = fmaxf(accS[4], accS[5]),   a3 = fmaxf(accS[6], accS[7]);
    float a4 = fmaxf(accS[8], accS[9]),   a5 = fmaxf(accS[10], accS[11]);
    float a6 = fmaxf(accS[12], accS[13]), a7 = fmaxf(accS[14], accS[15]);
    a0 = fmaxf(a0, a1); a2 = fmaxf(a2, a3); a4 = fmaxf(a4, a5); a6 = fmaxf(a6, a7);
    float mx = fmaxf(fmaxf(a0, a2), fmaxf(a4, a6));
    mx = fmaxf(mx, __shfl_xor(mx, 32));
    m_true = fmaxf(m_true, mx);
    const bool fold = __any(mx > m_run + SLACK);
    const float mn = fold ? fmaxf(m_run, mx) : m_run;
    float lsum = 0.0f;
    unsigned int pk[4][2];
    #pragma unroll
    for (int u = 0; u < 4; ++u) {
      const float p0 = exp2f(accS[4 * u + 0] - mn);
      const float p1 = exp2f(accS[4 * u + 1] - mn);
      const float p2 = exp2f(accS[4 * u + 2] - mn);
      const float p3 = exp2f(accS[4 * u + 3] - mn);
      lsum += (p0 + p1) + (p2 + p3);
      pk[u][0] = pkh(p0, p1);
      pk[u][1] = pkh(p2, p3);
    }
    lsum += __shfl_xor(lsum, 32);
    if (fold) {
      const float alpha = exp2f(m_run - mn);
      l_run = l_run * alpha + lsum;
      m_run = mn;
      #pragma unroll
      for (int mt = 0; mt < 4; ++mt)
        #pragma unroll
        for (int r = 0; r < 16; ++r) accO[mt][r] *= alpha;
    } else {
      l_run += lsum;
    }

    // ---- PV: O^T += V^T . P^T ----
    #pragma unroll
    for (int s = 0; s < 2; ++s) {
      const unsigned int s0 = pk[2 * s + (g ^ 1)][0];
      const unsigned int s1 = pk[2 * s + (g ^ 1)][1];
      const unsigned int t0 = __shfl_xor(s0, 32);
      const unsigned int t1 = __shfl_xor(s1, 32);
      union { unsigned int u[4]; h8v v; } bP;
      bP.u[0] = g ? t0 : pk[2 * s][0];
      bP.u[1] = g ? t1 : pk[2 * s][1];
      bP.u[2] = g ? pk[2 * s + 1][0] : t0;
      bP.u[3] = g ? pk[2 * s + 1][1] : t1;
      #pragma unroll
      for (int mt = 0; mt < 4; ++mt) {
        const int dr = 32 * mt + qlane;
        union { unsigned int u[4]; h8v v; } aV;
        const uint2 lo = *(const uint2*)&Vs[cur][dr * 36 + (2 * s + g) * 8];
        const uint2 hi = *(const uint2*)&Vs[cur][dr * 36 + (2 * s + g) * 8 + 4];
        aV.u[0] = lo.x; aV.u[1] = lo.y; aV.u[2] = hi.x; aV.u[3] = hi.y;
        accO[mt] = __builtin_amdgcn_mfma_f32_32x32x16_f16(aV.v, bP.v, accO[mt], 0, 0, 0);
      }
    }

    if (pre) {
      const int nb = cur ^ 1;
      #pragma unroll
      for (int i = 0; i < 2; ++i) {
        const int kr = (tid >> 4) + i * 16;
        *(uint4*)&Ks[nb][kr * 128 + ((tid & 15) ^ (kr & 15)) * 8] = stgK[i];
        const int idx = tid * 2 + i, dr = idx >> 2, cv = idx & 3;
        *(uint2*)&Vs[nb][dr * 36 + cv * 8]     = make_uint2(stgV[i].x, stgV[i].y);
        *(uint2*)&Vs[nb][dr * 36 + cv * 8 + 4] = make_uint2(stgV[i].z, stgV[i].w);
      }
    }
    __syncthreads();
  }

  // epilogue: renormalize to true max, store f16 partial O + (m,l)
  const float scale = exp2f(m_run - m_true);
  const int ncol = n0 + 32 * wv + qlane;
  const size_t obase = (size_t)(b * KS + spl) * ICH * NPOS;
  #pragma unroll
  for (int mt = 0; mt < 4; ++mt)
    #pragma unroll
    for (int r = 0; r < 16; ++r) {
      const int d = 32 * mt + (r & 3) + 8 * (r >> 2) + 4 * g;
      Opart[obase + (size_t)d * NPOS + ncol] = f2h(accO[mt][r] * scale);
    }
  if (g == 0) {
    Mpart[(size_t)(b * KS + spl) * NPOS + ncol] = m_true;
    Lpart[(size_t)(b * KS + spl) * NPOS + ncol] = l_run * scale;
  }
}

// ---------------------------------------------------------------------------
// mz_t<KS>: fused merge + zres, MFMA. grid (N/64, C/128=2, B) = 784 blocks.
// Per block: 128c x 64n. Wave wv owns c-tile wv (32c), both 32n tiles:
// acc[2]. Y staged f16 hi/lo [64n][24], Wz hi/lo [128c][24].
// ---------------------------------------------------------------------------
template <int KS>
__global__ __launch_bounds__(256, 2)
void mz_t(const float* __restrict__ x,
          const float* __restrict__ Wz,
          const unsigned short* __restrict__ Opart,
          const float* __restrict__ Mpart,
          const float* __restrict__ Lpart,
          float* __restrict__ out) {
  __shared__ float wgt[64][8];
  __shared__ unsigned short Yh[64][24], Yl[64][24];
  __shared__ unsigned short Wzh[128][24], Wzl[128][24];

  const int n0 = blockIdx.x * 64;
  const int c0 = blockIdx.y * 128;
  const int b  = blockIdx.z;
  const int tid = threadIdx.x;
  const int lane = tid & 63, wv = tid >> 6;
  const int ln = lane & 31, g = lane >> 5;

  if (tid < 64) {
    const int n = n0 + tid;
    float m[KS], l[KS];
    float M0 = -1e30f;
    #pragma unroll
    for (int s = 0; s < KS; ++s) {
      m[s] = Mpart[(size_t)(b * KS + s) * NPOS + n];
      l[s] = Lpart[(size_t)(b * KS + s) * NPOS + n];
      M0 = fmaxf(M0, m[s]);
    }
    float w[KS], lt = 0.0f;
    #pragma unroll
    for (int s = 0; s < KS; ++s) { w[s] = exp2f(m[s] - M0); lt += w[s] * l[s]; }
    const float inv = 1.0f / lt;
    #pragma unroll
    for (int s = 0; s < KS; ++s) wgt[tid][s] = w[s] * inv;
  }
  __syncthreads();

  // Y staging: n-pair np = tid&31 (n = 2np, 2np+1), ic-group icg = tid>>5
  // (2 ic each: ic = k0 + icg*2 + j).
  const int np  = tid & 31;
  const int icg = tid >> 5;
  float wA[KS], wB[KS];
  #pragma unroll
  for (int s = 0; s < KS; ++s) { wA[s] = wgt[2 * np][s]; wB[s] = wgt[2 * np + 1][s]; }
  // Wz staging: row wc = tid>>1, 8-k half wh
  const int wc = tid >> 1, wh = (tid & 1) * 8;
  const float* Wzrow = Wz + (size_t)(c0 + wc) * ICH + wh;

  fx16 acc[2];
  acc[0] = (fx16)(0.0f); acc[1] = (fx16)(0.0f);

  for (int k0 = 0; k0 < ICH; k0 += 16) {
    // ---- stage Wz chunk hi/lo: [c][k], one b128 write each ----
    {
      const float4 w0 = *(const float4*)&Wzrow[k0];
      const float4 w1 = *(const float4*)&Wzrow[k0 + 4];
      const float wv8[8] = {w0.x, w0.y, w0.z, w0.w, w1.x, w1.y, w1.z, w1.w};
      unsigned int hu[4], lu[4];
      #pragma unroll
      for (int q = 0; q < 4; ++q) {
        _Float16 h0 = (_Float16)wv8[2 * q], h1 = (_Float16)wv8[2 * q + 1];
        hu[q] = (unsigned int)__builtin_bit_cast(unsigned short, h0) |
                ((unsigned int)__builtin_bit_cast(unsigned short, h1) << 16);
        lu[q] = (unsigned int)f2h(wv8[2 * q] - (float)h0) |
                ((unsigned int)f2h(wv8[2 * q + 1] - (float)h1) << 16);
      }
      *(uint4*)&Wzh[wc][wh] = make_uint4(hu[0], hu[1], hu[2], hu[3]);
      *(uint4*)&Wzl[wc][wh] = make_uint4(lu[0], lu[1], lu[2], lu[3]);
    }
    // ---- stage merged Y chunk hi/lo: [n][k], ushort2 per n-row ----
    {
      unsigned short h0a[2], h1a[2], l0a[2], l1a[2];
      #pragma unroll
      for (int j = 0; j < 2; ++j) {
        const int ic = k0 + icg * 2 + j;
        float y0 = 0.0f, y1 = 0.0f;
        #pragma unroll
        for (int s = 0; s < KS; ++s) {
          const unsigned int u = *(const unsigned int*)
            &Opart[((size_t)(b * KS + s) * ICH + ic) * NPOS + n0 + 2 * np];
          y0 += wA[s] * h2f((unsigned short)(u & 0xffff));
          y1 += wB[s] * h2f((unsigned short)(u >> 16));
        }
        _Float16 hh0 = (_Float16)y0, hh1 = (_Float16)y1;
        h0a[j] = __builtin_bit_cast(unsigned short, hh0);
        h1a[j] = __builtin_bit_cast(unsigned short, hh1);
        l0a[j] = f2h(y0 - (float)hh0);
        l1a[j] = f2h(y1 - (float)hh1);
      }
      const int kc = icg * 2;
      *(ushort2*)&Yh[2 * np][kc]     = make_ushort2(h0a[0], h0a[1]);
      *(ushort2*)&Yh[2 * np + 1][kc] = make_ushort2(h1a[0], h1a[1]);
      *(ushort2*)&Yl[2 * np][kc]     = make_ushort2(l0a[0], l0a[1]);
      *(ushort2*)&Yl[2 * np + 1][kc] = make_ushort2(l1a[0], l1a[1]);
    }
    __syncthreads();

    // ---- MFMA: wave wv = c-tile wv; 2 n-tiles x 3 hi/lo terms ----
    const int cr = wv * 32 + ln;
    const h8v Ah = *(const h8v*)&Wzh[cr][g * 8];
    const h8v Al = *(const h8v*)&Wzl[cr][g * 8];
    #pragma unroll
    for (int ni = 0; ni < 2; ++ni) {
      const int nr = ni * 32 + ln;
      const h8v Bh = *(const h8v*)&Yh[nr][g * 8];
      const h8v Bl = *(const h8v*)&Yl[nr][g * 8];
      acc[ni] = __builtin_amdgcn_mfma_f32_32x32x16_f16(Ah, Bh, acc[ni], 0, 0, 0);
      acc[ni] = __builtin_amdgcn_mfma_f32_32x32x16_f16(Ah, Bl, acc[ni], 0, 0, 0);
      acc[ni] = __builtin_amdgcn_mfma_f32_32x32x16_f16(Al, Bh, acc[ni], 0, 0, 0);
    }
    __syncthreads();
  }

  // ---- epilogue: out = acc + x ----
  #pragma unroll
  for (int ni = 0; ni < 2; ++ni) {
    const int n = n0 + ni * 32 + ln;
    #pragma unroll
    for (int r = 0; r < 16; ++r) {
      const int c = c0 + wv * 32 + (r & 3) + 8 * (r >> 2) + 4 * g;
      const size_t base = ((size_t)(b * CCH + c)) * NPOS + n;
      out[base] = acc[ni][r] + x[base];
    }
  }
}

// ---------------------------------------------------------------------------
extern "C" void kernel_launch(void* const* d_in, const int* in_sizes, int n_in,
                              void* d_out, int out_size, void* d_ws, size_t ws_size,
                              hipStream_t stream) {
  const float* x      = (const float*)d_in[0];
  const float* Wg     = (const float*)d_in[1];
  const float* Wtheta = (const float*)d_in[2];
  const float* Wphi   = (const float*)d_in[3];
  const float* Wz     = (const float*)d_in[4];
  float* out = (float*)d_out;

  unsigned short* Qg    = (unsigned short*)d_ws;
  unsigned short* Kg    = Qg + BNIC;
  unsigned short* Vtg   = Kg + BNIC;
  unsigned short* Opart = Vtg + BNIC;

  // Whi/Wlo overlay the Opart region (dead until flash writes it).
  unsigned short* Whi = Opart;                           // 3*128*256 ushorts
  unsigned short* Wlo = Whi + 3 * 128 * 256;

  wconv<<<dim3(96), 256, 0, stream>>>(Wtheta, Wphi, Wg, Whi, Wlo);
  proj_mfma<<<dim3(NPOS / 32, BB), 256, 0, stream>>>(x, Whi, Wlo, Qg, Kg, Vtg);

  const size_t need7 = (3 + 7) * BNIC * 2 + (size_t)2 * 7 * BB * NPOS * 4;
  if (ws_size >= need7) {
    constexpr int KS = 7;
    float* Mpart = (float*)(Opart + (size_t)KS * BNIC);
    float* Lpart = Mpart + (size_t)KS * BB * NPOS;
    flash_t<KS><<<dim3(NPOS / 128, KS, BB), 256, 0, stream>>>(Qg, Kg, Vtg, Opart, Mpart, Lpart);
    mz_t<KS><<<dim3(NPOS / 64, CCH / 128, BB), 256, 0, stream>>>(x, Wz, Opart, Mpart, Lpart, out);
  } else {
    constexpr int KS = 4;
    float* Mpart = (float*)(Opart + (size_t)KS * BNIC);
    float* Lpart = Mpart + (size_t)KS * BB * NPOS;
    flash_t<KS><<<dim3(NPOS / 128, KS, BB), 256, 0, stream>>>(Qg, Kg, Vtg, Opart, Mpart, Lpart);
    mz_t<KS><<<dim3(NPOS / 64, CCH / 128, BB), 256, 0, stream>>>(x, Wz, Opart, Mpart, Lpart, out);
  }
}

// Round 11
// 282.860 us; speedup vs baseline: 1.1612x; 1.0458x over previous
//
#include <hip/hip_runtime.h>
#include <cstdint>

// SpacetimeNonLocalBlock: B=4, C=256, T*H*W=N=6272, IC=128.
// R18: flash is VALU-issue-bound (R17: VALUBusy 58% vs MfmaUtil 23% at 2
// waves/SIMD; launch_bounds(256,3) did NOT move occupancy). Fix: V LDS
// layout padded [128][36] -> granule-swizzled [128x4] 16B granules at
// dr*4 + (c ^ ((dr>>1)&3)): every V access one aligned b128 (was 2x b64 +
// 4 movs via union), staging 4x ds_write_b64 -> 2x ds_write_b128, LDS
// 34816 -> 32768 (probes a possible 32KB block-granularity threshold).
// Bank-verified conflict-free both sides. Bytes/math identical.
// KS=7 kept (R16 wave-starvation win), mz 64-n split kept (R17 win),
// proj/wconv = R15/R13 keepers.

#define BB   4
#define CCH  256
#define NPOS 6272
#define ICH  128
#define BNIC ((size_t)BB * NPOS * ICH)
#define TKF  32
#define SLACK 12.0f

typedef __attribute__((ext_vector_type(8)))  _Float16 h8v;  // 8 f16 MFMA frag
typedef __attribute__((ext_vector_type(16))) float fx16;    // 32x32 acc

__device__ __forceinline__ unsigned short f2h(float f) {
  _Float16 h = (_Float16)f;
  return __builtin_bit_cast(unsigned short, h);
}
__device__ __forceinline__ unsigned int pkh(float lo, float hi) {
  return __builtin_bit_cast(unsigned int, __builtin_amdgcn_cvt_pkrtz(lo, hi));
}
__device__ __forceinline__ float h2f(unsigned short u) {
  return (float)__builtin_bit_cast(_Float16, u);
}
// V granule offset (ushorts): row dr, logical 8-ushort chunk c -> swizzled.
__device__ __forceinline__ int vgoff(int dr, int c) {
  return (dr * 4 + (c ^ ((dr >> 1) & 3))) * 8;
}

// ---------------------------------------------------------------------------
// wconv: [Wtheta;Wphi;Wg] (3x128x256 f32) -> Whi/Wlo f16 split. grid 96.
// ---------------------------------------------------------------------------
__global__ __launch_bounds__(256, 1)
void wconv(const float* __restrict__ Wtheta, const float* __restrict__ Wphi,
           const float* __restrict__ Wg,
           unsigned short* __restrict__ Whi, unsigned short* __restrict__ Wlo) {
  const int idx4 = (blockIdx.x * 256 + threadIdx.x) * 4;   // [0, 98304) step 4
  const int p = idx4 >> 15;                                // 0,1,2 (128*256=32768)
  const float* W = (p == 0) ? Wtheta : (p == 1) ? Wphi : Wg;
  const float4 v = *(const float4*)&W[idx4 - (p << 15)];
  const float vv[4] = {v.x, v.y, v.z, v.w};
  ushort4 h, l;
  unsigned short* hp = (unsigned short*)&h;
  unsigned short* lp = (unsigned short*)&l;
  #pragma unroll
  for (int q = 0; q < 4; ++q) {
    _Float16 hh = (_Float16)vv[q];
    hp[q] = __builtin_bit_cast(unsigned short, hh);
    lp[q] = f2h(vv[q] - (float)hh);
  }
  *(ushort4*)&Whi[idx4] = h;
  *(ushort4*)&Wlo[idx4] = l;
}

// ---------------------------------------------------------------------------
// proj_mfma (R15 keeper): grid (N/32, B), 256 thr. c-step 32 per epoch,
// x staged f16 hi/lo [32n][40c-stride] (b128 reads conflict-free).
// ---------------------------------------------------------------------------
__global__ __launch_bounds__(256, 2)
void proj_mfma(const float* __restrict__ x,
               const unsigned short* __restrict__ Whi,
               const unsigned short* __restrict__ Wlo,
               unsigned short* __restrict__ Qg,
               unsigned short* __restrict__ Kg,
               unsigned short* __restrict__ Vtg) {
  __shared__ unsigned short Xhi[32][40];
  __shared__ unsigned short Xlo[32][40];
  const int n0 = blockIdx.x * 32;
  const int b  = blockIdx.y;
  const int tid = threadIdx.x;
  const int lane = tid & 63, wv = tid >> 6;
  const int ln = lane & 31, g = lane >> 5;

  fx16 acc[3];
  acc[0] = (fx16)(0.0f); acc[1] = (fx16)(0.0f); acc[2] = (fx16)(0.0f);

  const int sn = tid & 31, cq = (tid >> 5) * 4;
  const float* xp = x + ((size_t)b * CCH + cq) * NPOS + n0 + sn;

  float pv[4];
  #pragma unroll
  for (int q = 0; q < 4; ++q) pv[q] = xp[(size_t)q * NPOS];

  for (int c0 = 0; c0 < CCH; c0 += 32) {
    {
      ushort4 h4, l4;
      unsigned short* hp = (unsigned short*)&h4;
      unsigned short* lp = (unsigned short*)&l4;
      #pragma unroll
      for (int q = 0; q < 4; ++q) {
        _Float16 hh = (_Float16)pv[q];
        hp[q] = __builtin_bit_cast(unsigned short, hh);
        lp[q] = f2h(pv[q] - (float)hh);
      }
      *(ushort4*)&Xhi[sn][cq] = h4;
      *(ushort4*)&Xlo[sn][cq] = l4;
    }
    if (c0 + 32 < CCH) {
      #pragma unroll
      for (int q = 0; q < 4; ++q) pv[q] = xp[(size_t)(c0 + 32 + q) * NPOS];
    }
    __syncthreads();
    #pragma unroll
    for (int kc = 0; kc < 2; ++kc) {
      const h8v bxh = *(const h8v*)&Xhi[ln][kc * 16 + g * 8];
      const h8v bxl = *(const h8v*)&Xlo[ln][kc * 16 + g * 8];
      #pragma unroll
      for (int t = 0; t < 3; ++t) {
        const int T = wv * 3 + t;
        const size_t wb = ((size_t)(T * 32 + ln)) * CCH + c0 + kc * 16 + g * 8;
        const h8v ah = *(const h8v*)&Whi[wb];
        const h8v al = *(const h8v*)&Wlo[wb];
        acc[t] = __builtin_amdgcn_mfma_f32_32x32x16_f16(ah, bxh, acc[t], 0, 0, 0);
        acc[t] = __builtin_amdgcn_mfma_f32_32x32x16_f16(ah, bxl, acc[t], 0, 0, 0);
        acc[t] = __builtin_amdgcn_mfma_f32_32x32x16_f16(al, bxh, acc[t], 0, 0, 0);
      }
    }
    __syncthreads();
  }

  const float LOG2E = 1.4426950408889634f;
  const int n = n0 + ln;
  #pragma unroll
  for (int t = 0; t < 3; ++t) {
    const int T = wv * 3 + t;
    const int p = T >> 2;
    const int ot = (T & 3) * 32;
    if (p < 2) {
      unsigned short* Out = (p == 0) ? Qg : Kg;
      const float scl = (p == 0) ? LOG2E : 1.0f;
      #pragma unroll
      for (int q = 0; q < 4; ++q) {
        ushort4 v;
        v.x = f2h(acc[t][4 * q + 0] * scl);
        v.y = f2h(acc[t][4 * q + 1] * scl);
        v.z = f2h(acc[t][4 * q + 2] * scl);
        v.w = f2h(acc[t][4 * q + 3] * scl);
        *(ushort4*)&Out[((size_t)b * NPOS + n) * ICH + ot + 8 * q + 4 * g] = v;
      }
    } else {
      #pragma unroll
      for (int r = 0; r < 16; ++r) {
        const int o = ot + (r & 3) + 8 * (r >> 2) + 4 * g;
        Vtg[((size_t)b * ICH + o) * NPOS + n] = f2h(acc[t][r]);
      }
    }
  }
}

// ---------------------------------------------------------------------------
// flash_t<KS>: flash10 body, V in granule-swizzled LDS (single-b128 access).
// grid (49, KS, B). LDS 32 KB: Ks[2][32x128] 4-bit swz, Vs[2][128x32] swz.
// ---------------------------------------------------------------------------
template <int KS>
__global__ __launch_bounds__(256, 3)
void flash_t(const unsigned short* __restrict__ Qg,
             const unsigned short* __restrict__ Kg,
             const unsigned short* __restrict__ Vtg,
             unsigned short* __restrict__ Opart,
             float* __restrict__ Mpart,
             float* __restrict__ Lpart) {
  constexpr int KLEN = NPOS / KS;
  constexpr int NIT  = KLEN / TKF;
  __shared__ unsigned short Ks[2][TKF * 128];   // 8 KB per buf
  __shared__ unsigned short Vs[2][128 * 32];    // 8 KB per buf (swizzled)

  const int b   = blockIdx.z;
  const int spl = blockIdx.y;
  const int n0  = blockIdx.x * 128;
  const int kb  = spl * KLEN;
  const int tid = threadIdx.x;
  const int lane = tid & 63, wv = tid >> 6;
  const int qlane = lane & 31, g = lane >> 5;
  const int swz = qlane & 15;

  h8v qf[8];
  {
    const size_t qbase = ((size_t)b * NPOS + n0 + 32 * wv + qlane) * ICH;
    #pragma unroll
    for (int cs = 0; cs < 8; ++cs)
      qf[cs] = *(const h8v*)&Qg[qbase + cs * 16 + g * 8];
  }

  {
    #pragma unroll
    for (int i = 0; i < 2; ++i) {
      const int kr = (tid >> 4) + i * 16, c = tid & 15;
      const uint4 v = *(const uint4*)&Kg[((size_t)b * NPOS + kb + kr) * ICH + c * 8];
      *(uint4*)&Ks[0][kr * 128 + (c ^ (kr & 15)) * 8] = v;
      const int idx = tid * 2 + i, dr = idx >> 2, cv = idx & 3;
      const uint4 w = *(const uint4*)&Vtg[((size_t)b * ICH + dr) * NPOS + kb + cv * 8];
      *(uint4*)&Vs[0][vgoff(dr, cv)] = w;
    }
  }
  __syncthreads();

  float m_run = -1e30f, m_true = -1e30f, l_run = 0.0f;
  fx16 accO[4];
  #pragma unroll
  for (int mt = 0; mt < 4; ++mt) accO[mt] = (fx16)(0.0f);

  uint4 stgK[2], stgV[2];

  for (int it = 0; it < NIT; ++it) {
    const int cur = it & 1;
    const bool pre = (it + 1 < NIT);
    if (pre) {
      const int k0n = kb + (it + 1) * TKF;
      #pragma unroll
      for (int i = 0; i < 2; ++i) {
        const int kr = (tid >> 4) + i * 16;
        stgK[i] = *(const uint4*)&Kg[((size_t)b * NPOS + k0n + kr) * ICH + (tid & 15) * 8];
        const int idx = tid * 2 + i, dr = idx >> 2, cv = idx & 3;
        stgV[i] = *(const uint4*)&Vtg[((size_t)b * ICH + dr) * NPOS + k0n + cv * 8];
      }
    }

    // ---- S^T = K . Q^T ----
    fx16 accS = (fx16)(0.0f);
    #pragma unroll
    for (int cs = 0; cs < 8; ++cs) {
      const h8v aK = *(const h8v*)&Ks[cur][qlane * 128 + ((2 * cs + g) ^ swz) * 8];
      accS = __builtin_amdgcn_mfma_f32_32x32x16_f16(aK, qf[cs], accS, 0, 0, 0);
    }

    // ---- slack-fold online softmax (log2 domain), tree max ----
    float a0 = fmaxf(accS[0], accS[1]),   a1 = fmaxf(accS[2], accS[3]);
    float a2 = fmaxf(accS[4], accS[5]),   a3 = fmaxf(accS[6], accS[7]);
    float a4 = fmaxf(accS[8], accS[9]),   a5 = fmaxf(accS[10], accS[11]);
    float a6 = fmaxf(accS[12], accS[13]), a7 = fmaxf(accS[14], accS[15]);
    a0 = fmaxf(a0, a1); a2 = fmaxf(a2, a3); a4 = fmaxf(a4, a5); a6 = fmaxf(a6, a7);
    float mx = fmaxf(fmaxf(a0, a2), fmaxf(a4, a6));
    mx = fmaxf(mx, __shfl_xor(mx, 32));
    m_true = fmaxf(m_true, mx);
    const bool fold = __any(mx > m_run + SLACK);
    const float mn = fold ? fmaxf(m_run, mx) : m_run;
    float lsum = 0.0f;
    unsigned int pk[4][2];
    #pragma unroll
    for (int u = 0; u < 4; ++u) {
      const float p0 = exp2f(accS[4 * u + 0] - mn);
      const float p1 = exp2f(accS[4 * u + 1] - mn);
      const float p2 = exp2f(accS[4 * u + 2] - mn);
      const float p3 = exp2f(accS[4 * u + 3] - mn);
      lsum += (p0 + p1) + (p2 + p3);
      pk[u][0] = pkh(p0, p1);
      pk[u][1] = pkh(p2, p3);
    }
    lsum += __shfl_xor(lsum, 32);
    if (fold) {
      const float alpha = exp2f(m_run - mn);
      l_run = l_run * alpha + lsum;
      m_run = mn;
      #pragma unroll
      for (int mt = 0; mt < 4; ++mt)
        #pragma unroll
        for (int r = 0; r < 16; ++r) accO[mt][r] *= alpha;
    } else {
      l_run += lsum;
    }

    // ---- PV: O^T += V^T . P^T ----
    #pragma unroll
    for (int s = 0; s < 2; ++s) {
      const unsigned int s0 = pk[2 * s + (g ^ 1)][0];
      const unsigned int s1 = pk[2 * s + (g ^ 1)][1];
      const unsigned int t0 = __shfl_xor(s0, 32);
      const unsigned int t1 = __shfl_xor(s1, 32);
      union { unsigned int u[4]; h8v v; } bP;
      bP.u[0] = g ? t0 : pk[2 * s][0];
      bP.u[1] = g ? t1 : pk[2 * s][1];
      bP.u[2] = g ? pk[2 * s + 1][0] : t0;
      bP.u[3] = g ? pk[2 * s + 1][1] : t1;
      #pragma unroll
      for (int mt = 0; mt < 4; ++mt) {
        const h8v aV = *(const h8v*)&Vs[cur][vgoff(32 * mt + qlane, 2 * s + g)];
        accO[mt] = __builtin_amdgcn_mfma_f32_32x32x16_f16(aV, bP.v, accO[mt], 0, 0, 0);
      }
    }

    if (pre) {
      const int nb = cur ^ 1;
      #pragma unroll
      for (int i = 0; i < 2; ++i) {
        const int kr = (tid >> 4) + i * 16;
        *(uint4*)&Ks[nb][kr * 128 + ((tid & 15) ^ (kr & 15)) * 8] = stgK[i];
        const int idx = tid * 2 + i, dr = idx >> 2, cv = idx & 3;
        *(uint4*)&Vs[nb][vgoff(dr, cv)] = stgV[i];
      }
    }
    __syncthreads();
  }

  // epilogue: renormalize to true max, store f16 partial O + (m,l)
  const float scale = exp2f(m_run - m_true);
  const int ncol = n0 + 32 * wv + qlane;
  const size_t obase = (size_t)(b * KS + spl) * ICH * NPOS;
  #pragma unroll
  for (int mt = 0; mt < 4; ++mt)
    #pragma unroll
    for (int r = 0; r < 16; ++r) {
      const int d = 32 * mt + (r & 3) + 8 * (r >> 2) + 4 * g;
      Opart[obase + (size_t)d * NPOS + ncol] = f2h(accO[mt][r] * scale);
    }
  if (g == 0) {
    Mpart[(size_t)(b * KS + spl) * NPOS + ncol] = m_true;
    Lpart[(size_t)(b * KS + spl) * NPOS + ncol] = l_run * scale;
  }
}

// ---------------------------------------------------------------------------
// mz_t<KS> (R17 keeper): fused merge + zres, MFMA. grid (N/64, 2, B).
// ---------------------------------------------------------------------------
template <int KS>
__global__ __launch_bounds__(256, 2)
void mz_t(const float* __restrict__ x,
          const float* __restrict__ Wz,
          const unsigned short* __restrict__ Opart,
          const float* __restrict__ Mpart,
          const float* __restrict__ Lpart,
          float* __restrict__ out) {
  __shared__ float wgt[64][8];
  __shared__ unsigned short Yh[64][24], Yl[64][24];
  __shared__ unsigned short Wzh[128][24], Wzl[128][24];

  const int n0 = blockIdx.x * 64;
  const int c0 = blockIdx.y * 128;
  const int b  = blockIdx.z;
  const int tid = threadIdx.x;
  const int lane = tid & 63, wv = tid >> 6;
  const int ln = lane & 31, g = lane >> 5;

  if (tid < 64) {
    const int n = n0 + tid;
    float m[KS], l[KS];
    float M0 = -1e30f;
    #pragma unroll
    for (int s = 0; s < KS; ++s) {
      m[s] = Mpart[(size_t)(b * KS + s) * NPOS + n];
      l[s] = Lpart[(size_t)(b * KS + s) * NPOS + n];
      M0 = fmaxf(M0, m[s]);
    }
    float w[KS], lt = 0.0f;
    #pragma unroll
    for (int s = 0; s < KS; ++s) { w[s] = exp2f(m[s] - M0); lt += w[s] * l[s]; }
    const float inv = 1.0f / lt;
    #pragma unroll
    for (int s = 0; s < KS; ++s) wgt[tid][s] = w[s] * inv;
  }
  __syncthreads();

  const int np  = tid & 31;
  const int icg = tid >> 5;
  float wA[KS], wB[KS];
  #pragma unroll
  for (int s = 0; s < KS; ++s) { wA[s] = wgt[2 * np][s]; wB[s] = wgt[2 * np + 1][s]; }
  const int wc = tid >> 1, wh = (tid & 1) * 8;
  const float* Wzrow = Wz + (size_t)(c0 + wc) * ICH + wh;

  fx16 acc[2];
  acc[0] = (fx16)(0.0f); acc[1] = (fx16)(0.0f);

  for (int k0 = 0; k0 < ICH; k0 += 16) {
    {
      const float4 w0 = *(const float4*)&Wzrow[k0];
      const float4 w1 = *(const float4*)&Wzrow[k0 + 4];
      const float wv8[8] = {w0.x, w0.y, w0.z, w0.w, w1.x, w1.y, w1.z, w1.w};
      unsigned int hu[4], lu[4];
      #pragma unroll
      for (int q = 0; q < 4; ++q) {
        _Float16 h0 = (_Float16)wv8[2 * q], h1 = (_Float16)wv8[2 * q + 1];
        hu[q] = (unsigned int)__builtin_bit_cast(unsigned short, h0) |
                ((unsigned int)__builtin_bit_cast(unsigned short, h1) << 16);
        lu[q] = (unsigned int)f2h(wv8[2 * q] - (float)h0) |
                ((unsigned int)f2h(wv8[2 * q + 1] - (float)h1) << 16);
      }
      *(uint4*)&Wzh[wc][wh] = make_uint4(hu[0], hu[1], hu[2], hu[3]);
      *(uint4*)&Wzl[wc][wh] = make_uint4(lu[0], lu[1], lu[2], lu[3]);
    }
    {
      unsigned short h0a[2], h1a[2], l0a[2], l1a[2];
      #pragma unroll
      for (int j = 0; j < 2; ++j) {
        const int ic = k0 + icg * 2 + j;
        float y0 = 0.0f, y1 = 0.0f;
        #pragma unroll
        for (int s = 0; s < KS; ++s) {
          const unsigned int u = *(const unsigned int*)
            &Opart[((size_t)(b * KS + s) * ICH + ic) * NPOS + n0 + 2 * np];
          y0 += wA[s] * h2f((unsigned short)(u & 0xffff));
          y1 += wB[s] * h2f((unsigned short)(u >> 16));
        }
        _Float16 hh0 = (_Float16)y0, hh1 = (_Float16)y1;
        h0a[j] = __builtin_bit_cast(unsigned short, hh0);
        h1a[j] = __builtin_bit_cast(unsigned short, hh1);
        l0a[j] = f2h(y0 - (float)hh0);
        l1a[j] = f2h(y1 - (float)hh1);
      }
      const int kc = icg * 2;
      *(ushort2*)&Yh[2 * np][kc]     = make_ushort2(h0a[0], h0a[1]);
      *(ushort2*)&Yh[2 * np + 1][kc] = make_ushort2(h1a[0], h1a[1]);
      *(ushort2*)&Yl[2 * np][kc]     = make_ushort2(l0a[0], l0a[1]);
      *(ushort2*)&Yl[2 * np + 1][kc] = make_ushort2(l1a[0], l1a[1]);
    }
    __syncthreads();

    const int cr = wv * 32 + ln;
    const h8v Ah = *(const h8v*)&Wzh[cr][g * 8];
    const h8v Al = *(const h8v*)&Wzl[cr][g * 8];
    #pragma unroll
    for (int ni = 0; ni < 2; ++ni) {
      const int nr = ni * 32 + ln;
      const h8v Bh = *(const h8v*)&Yh[nr][g * 8];
      const h8v Bl = *(const h8v*)&Yl[nr][g * 8];
      acc[ni] = __builtin_amdgcn_mfma_f32_32x32x16_f16(Ah, Bh, acc[ni], 0, 0, 0);
      acc[ni] = __builtin_amdgcn_mfma_f32_32x32x16_f16(Ah, Bl, acc[ni], 0, 0, 0);
      acc[ni] = __builtin_amdgcn_mfma_f32_32x32x16_f16(Al, Bh, acc[ni], 0, 0, 0);
    }
    __syncthreads();
  }

  #pragma unroll
  for (int ni = 0; ni < 2; ++ni) {
    const int n = n0 + ni * 32 + ln;
    #pragma unroll
    for (int r = 0; r < 16; ++r) {
      const int c = c0 + wv * 32 + (r & 3) + 8 * (r >> 2) + 4 * g;
      const size_t base = ((size_t)(b * CCH + c)) * NPOS + n;
      out[base] = acc[ni][r] + x[base];
    }
  }
}

// ---------------------------------------------------------------------------
extern "C" void kernel_launch(void* const* d_in, const int* in_sizes, int n_in,
                              void* d_out, int out_size, void* d_ws, size_t ws_size,
                              hipStream_t stream) {
  const float* x      = (const float*)d_in[0];
  const float* Wg     = (const float*)d_in[1];
  const float* Wtheta = (const float*)d_in[2];
  const float* Wphi   = (const float*)d_in[3];
  const float* Wz     = (const float*)d_in[4];
  float* out = (float*)d_out;

  unsigned short* Qg    = (unsigned short*)d_ws;
  unsigned short* Kg    = Qg + BNIC;
  unsigned short* Vtg   = Kg + BNIC;
  unsigned short* Opart = Vtg + BNIC;

  // Whi/Wlo overlay the Opart region (dead until flash writes it).
  unsigned short* Whi = Opart;                           // 3*128*256 ushorts
  unsigned short* Wlo = Whi + 3 * 128 * 256;

  wconv<<<dim3(96), 256, 0, stream>>>(Wtheta, Wphi, Wg, Whi, Wlo);
  proj_mfma<<<dim3(NPOS / 32, BB), 256, 0, stream>>>(x, Whi, Wlo, Qg, Kg, Vtg);

  const size_t need7 = (3 + 7) * BNIC * 2 + (size_t)2 * 7 * BB * NPOS * 4;
  if (ws_size >= need7) {
    constexpr int KS = 7;
    float* Mpart = (float*)(Opart + (size_t)KS * BNIC);
    float* Lpart = Mpart + (size_t)KS * BB * NPOS;
    flash_t<KS><<<dim3(NPOS / 128, KS, BB), 256, 0, stream>>>(Qg, Kg, Vtg, Opart, Mpart, Lpart);
    mz_t<KS><<<dim3(NPOS / 64, CCH / 128, BB), 256, 0, stream>>>(x, Wz, Opart, Mpart, Lpart, out);
  } else {
    constexpr int KS = 4;
    float* Mpart = (float*)(Opart + (size_t)KS * BNIC);
    float* Lpart = Mpart + (size_t)KS * BB * NPOS;
    flash_t<KS><<<dim3(NPOS / 128, KS, BB), 256, 0, stream>>>(Qg, Kg, Vtg, Opart, Mpart, Lpart);
    mz_t<KS><<<dim3(NPOS / 64, CCH / 128, BB), 256, 0, stream>>>(x, Wz, Opart, Mpart, Lpart, out);
  }
}